// Round 4
// baseline (1420.840 us; speedup 1.0000x reference)
//
#include <hip/hip_runtime.h>
#include <cstdint>
#include <cstddef>

// ---------------- constants ----------------
#define SEQ     4096
#define IN_DIM  1024
#define D_MODEL 512
#define D_INNER 1024
#define D_STATE 16
#define DT_RANK 32

#define CHUNK   64
#define NCHUNK  64     // SEQ / CHUNK
#define NREC    16384  // D_INNER * D_STATE

// workspace layout (float offsets) -- identical footprint to rounds 1-3 (known-safe)
static const size_t OFF_H     = 0;                      // 4096*512
static const size_t OFF_HN    = 2097152;                // hn; P(+0)/carry(+1048576); later resid-temp
static const size_t OFF_XCRAW = 4194304;                // xcraw, later y
static const size_t OFF_Z     = 8388608;                // z raw -> silu(z) in place
static const size_t OFF_XC    = 12582912;               // xc (post conv+silu)
static const size_t OFF_DT    = 16777216;               // dt
static const size_t OFF_DBC   = 20971520;               // 4096*64
static const size_t OFF_S     = OFF_DBC + 262144;
static const size_t OFF_WOUT  = OFF_S + 1048576;
static const size_t OFF_PART  = OFF_WOUT + 1048576;

// ---------------- jax threefry / normal reproduction ----------------
__device__ __forceinline__ uint32_t rotl32(uint32_t v, int r) { return (v << r) | (v >> (32 - r)); }

__device__ __forceinline__ void threefry2x32(uint32_t k0, uint32_t k1, uint32_t x0, uint32_t x1,
                                             uint32_t& o0, uint32_t& o1) {
  uint32_t ks0 = k0, ks1 = k1, ks2 = k0 ^ k1 ^ 0x1BD11BDAu;
  x0 += ks0; x1 += ks1;
  const int rotA[4] = {13, 15, 26, 6};
  const int rotB[4] = {17, 29, 16, 24};
  uint32_t ks[3] = {ks0, ks1, ks2};
#pragma unroll
  for (int r = 0; r < 5; ++r) {
    const int* rr = (r & 1) ? rotB : rotA;
#pragma unroll
    for (int j = 0; j < 4; ++j) { x0 += x1; x1 = rotl32(x1, rr[j]); x1 ^= x0; }
    x0 += ks[(r + 1) % 3];
    x1 += ks[(r + 2) % 3] + (uint32_t)(r + 1);
  }
  o0 = x0; o1 = x1;
}

__device__ __forceinline__ float erfinv32(float x) {
  float w = -log1pf(-x * x);
  float p;
  if (w < 5.0f) {
    w -= 2.5f;
    p = 2.81022636e-08f;
    p = fmaf(p, w, 3.43273939e-07f);
    p = fmaf(p, w, -3.5233877e-06f);
    p = fmaf(p, w, -4.39150654e-06f);
    p = fmaf(p, w, 0.00021858087f);
    p = fmaf(p, w, -0.00125372503f);
    p = fmaf(p, w, -0.00417768164f);
    p = fmaf(p, w, 0.246640727f);
    p = fmaf(p, w, 1.50140941f);
  } else {
    w = sqrtf(w) - 3.0f;
    p = -0.000200214257f;
    p = fmaf(p, w, 0.000100950558f);
    p = fmaf(p, w, 0.00134934322f);
    p = fmaf(p, w, -0.00367342844f);
    p = fmaf(p, w, 0.00573950773f);
    p = fmaf(p, w, -0.0076224613f);
    p = fmaf(p, w, 0.00943887047f);
    p = fmaf(p, w, 1.00167406f);
    p = fmaf(p, w, 2.83297682f);
  }
  return p * x;
}

__device__ __forceinline__ float bits_to_normal(uint32_t b) {
  float f = __uint_as_float((b >> 9) | 0x3f800000u) - 1.0f;
  const float lo = -0.99999994f;
  float u = f * (1.0f - lo) + lo;
  u = fmaxf(lo, u);
  return 1.41421356f * erfinv32(u);
}

// NEW (v4): PARTITIONABLE threefry bits (jax_threefry_partitionable=True, the modern default).
// bits[j] = o0 ^ o1 where (o0,o1) = threefry(folded_key, (hi(j64)=0, lo(j64)=j)).
__global__ __launch_bounds__(256) void gen_wout(float* __restrict__ w) {
  int gid = blockIdx.x * 256 + threadIdx.x;        // [0, 2*524288)
  int layer = gid >> 19;
  int j = gid & 0x7FFFF;                           // [0, 524288)
  uint32_t k0, k1;
  threefry2x32(0u, 7u, 0u, (uint32_t)layer, k0, k1);   // fold_in(key(7), layer)
  uint32_t o0, o1;
  threefry2x32(k0, k1, 0u, (uint32_t)j, o0, o1);       // counts64 = j -> (hi=0, lo=j)
  w[(size_t)layer * 524288 + j] = bits_to_normal(o0 ^ o1) * 0.02f;
}

// ---------------- activations ----------------
__device__ __forceinline__ double silu_d(double v) { return v / (1.0 + exp(-v)); }
__device__ __forceinline__ double gelu_d(double v) {
  double v3 = v * v * v;
  return 0.5 * v * (1.0 + tanh(0.7978845608028654 * (v + 0.044715 * v3)));
}
__device__ __forceinline__ double softplus_d(double v) {
  return fmax(v, 0.0) + log1p(exp(-fabs(v)));
}
__device__ __forceinline__ float silu_f(float v) { return v / (1.0f + expf(-v)); }

// ---------------- tiled GEMM (f32 data, f64 accumulate): C = A[M,K] * B[N,K]^T ----------------
enum { EPI_NONE = 0, EPI_BIAS_GELU = 1, EPI_SOFTPLUS = 3 };

template <int EPI>
__global__ __launch_bounds__(256) void gemm_abt(
    const float* __restrict__ A, int lda,
    const float* __restrict__ B, int ldb,
    float* __restrict__ C, int ldc, int K,
    const float* __restrict__ bias) {
  __shared__ float As[32][68];
  __shared__ float Bs[32][68];
  const int m0 = blockIdx.y * 64, n0 = blockIdx.x * 64;
  const int tid = threadIdx.x;
  const int tm = tid >> 4, tn = tid & 15;
  double acc[4][4] = {};
  for (int k0 = 0; k0 < K; k0 += 32) {
#pragma unroll
    for (int it = 0; it < 2; ++it) {
      int ff = tid + it * 256;
      int row = ff >> 3, kq = ff & 7;
      const float4 va = *(const float4*)(A + (size_t)(m0 + row) * lda + k0 + kq * 4);
      As[kq * 4 + 0][row] = va.x; As[kq * 4 + 1][row] = va.y;
      As[kq * 4 + 2][row] = va.z; As[kq * 4 + 3][row] = va.w;
      const float4 vb = *(const float4*)(B + (size_t)(n0 + row) * ldb + k0 + kq * 4);
      Bs[kq * 4 + 0][row] = vb.x; Bs[kq * 4 + 1][row] = vb.y;
      Bs[kq * 4 + 2][row] = vb.z; Bs[kq * 4 + 3][row] = vb.w;
    }
    __syncthreads();
#pragma unroll
    for (int k = 0; k < 32; ++k) {
      const float4 a4 = *(const float4*)&As[k][tm * 4];
      const float4 b4 = *(const float4*)&Bs[k][tn * 4];
      const double av[4] = {(double)a4.x, (double)a4.y, (double)a4.z, (double)a4.w};
      const double bv[4] = {(double)b4.x, (double)b4.y, (double)b4.z, (double)b4.w};
#pragma unroll
      for (int i_ = 0; i_ < 4; ++i_)
#pragma unroll
        for (int j_ = 0; j_ < 4; ++j_)
          acc[i_][j_] = fma(av[i_], bv[j_], acc[i_][j_]);
    }
    __syncthreads();
  }
#pragma unroll
  for (int i_ = 0; i_ < 4; ++i_) {
    int m = m0 + tm * 4 + i_;
#pragma unroll
    for (int j_ = 0; j_ < 4; ++j_) {
      int n = n0 + tn * 4 + j_;
      double v = acc[i_][j_];
      if (EPI == EPI_NONE) {
        C[(size_t)m * ldc + n] = (float)v;
      } else if (EPI == EPI_BIAS_GELU) {
        v += (double)bias[n];
        C[(size_t)m * ldc + n] = (float)gelu_d(v);
      } else if (EPI == EPI_SOFTPLUS) {
        v += (double)bias[n];
        C[(size_t)m * ldc + n] = (float)softplus_d(v);
      }
    }
  }
}

// ---------------- layernorm ----------------
__global__ __launch_bounds__(256) void ln_rows(const float* __restrict__ in,
                                               const float* __restrict__ w,
                                               const float* __restrict__ b,
                                               float* __restrict__ out) {
  __shared__ double red[4];
  const int row = blockIdx.x, t = threadIdx.x;
  const float* r = in + (size_t)row * D_MODEL;
  double x0 = (double)r[t], x1 = (double)r[t + 256];
  double s = x0 + x1;
#pragma unroll
  for (int o = 32; o >= 1; o >>= 1) s += __shfl_down(s, o);
  int wid = t >> 6, lane = t & 63;
  if (lane == 0) red[wid] = s;
  __syncthreads();
  double mu = (red[0] + red[1] + red[2] + red[3]) * (1.0 / 512.0);
  __syncthreads();
  double d0 = x0 - mu, d1 = x1 - mu;
  double v = d0 * d0 + d1 * d1;
#pragma unroll
  for (int o = 32; o >= 1; o >>= 1) v += __shfl_down(v, o);
  if (lane == 0) red[wid] = v;
  __syncthreads();
  double var = (red[0] + red[1] + red[2] + red[3]) * (1.0 / 512.0);
  double rs = rsqrt(var + 1e-5);
  out[(size_t)row * D_MODEL + t]       = (float)(d0 * rs * (double)w[t] + (double)b[t]);
  out[(size_t)row * D_MODEL + t + 256] = (float)(d1 * rs * (double)w[t + 256] + (double)b[t + 256]);
}

// ---------------- elementwise silu in place ----------------
__global__ __launch_bounds__(256) void silu_inplace(float* __restrict__ z) {
  int idx = blockIdx.x * 256 + threadIdx.x;
  float v = z[idx];
  z[idx] = v / (1.0f + expf(-v));
}

// ---------------- causal depthwise conv + bias + silu ----------------
__global__ __launch_bounds__(256) void conv_silu2(const float* __restrict__ xcr,
                                                  const float* __restrict__ cw,
                                                  const float* __restrict__ cb,
                                                  float* __restrict__ out) {
  const int l = blockIdx.x;  // [0, 4096)
  for (int q = 0; q < 4; ++q) {
    const int d = threadIdx.x + q * 256;
    float acc = cb[d];
#pragma unroll
    for (int k = 0; k < 4; ++k) {
      const int ll = l + k - 3;
      const float xv = (ll >= 0) ? xcr[(size_t)ll * D_INNER + d] : 0.0f;
      acc = fmaf(xv, cw[d * 4 + k], acc);
    }
    out[(size_t)l * D_INNER + d] = acc / (1.0f + expf(-acc));
  }
}

// ---------------- selective scan (3-pass chunked) ----------------
__global__ __launch_bounds__(256) void scanA(const float* __restrict__ dt,
                                             const float* __restrict__ dbc,
                                             const float* __restrict__ xc,
                                             const float* __restrict__ Alog,
                                             float* __restrict__ P, float* __restrict__ S) {
  const int dg = blockIdx.x, c = blockIdx.y;
  const int n = threadIdx.x & 15, dd = threadIdx.x >> 4;
  const int d = dg * 16 + dd;
  const float a = -expf(Alog[d * 16 + n]);
  float p = 1.0f, s = 0.0f;
  const int l0 = c * CHUNK;
  for (int t = 0; t < CHUNK; ++t) {
    int l = l0 + t;
    float dtv = dt[(size_t)l * D_INNER + d];
    float bv = dbc[(size_t)l * 64 + DT_RANK + n];
    float xv = xc[(size_t)l * D_INNER + d];
    float da = expf(dtv * a);
    s = fmaf(da, s, dtv * bv * xv);
    p *= da;
  }
  int idx = c * NREC + d * 16 + n;
  P[idx] = p; S[idx] = s;
}

__global__ __launch_bounds__(256) void scanB(const float* __restrict__ P,
                                             const float* __restrict__ S,
                                             float* __restrict__ carry) {
  int idx = blockIdx.x * 256 + threadIdx.x;
  float cr = 0.0f;
  for (int c = 0; c < NCHUNK; ++c) {
    int k = c * NREC + idx;
    carry[k] = cr;
    cr = fmaf(P[k], cr, S[k]);
  }
}

// emits ONLY the scan term ys = sum_n s*C
__global__ __launch_bounds__(256) void scanC2(const float* __restrict__ dt,
                                              const float* __restrict__ dbc,
                                              const float* __restrict__ xc,
                                              const float* __restrict__ Alog,
                                              const float* __restrict__ carry,
                                              float* __restrict__ ys) {
  const int dg = blockIdx.x, c = blockIdx.y;
  const int n = threadIdx.x & 15, dd = threadIdx.x >> 4;
  const int d = dg * 16 + dd;
  const float a = -expf(Alog[d * 16 + n]);
  float s = carry[c * NREC + d * 16 + n];
  const int l0 = c * CHUNK;
  for (int t = 0; t < CHUNK; ++t) {
    int l = l0 + t;
    float dtv = dt[(size_t)l * D_INNER + d];
    float bv = dbc[(size_t)l * 64 + DT_RANK + n];
    float cv = dbc[(size_t)l * 64 + DT_RANK + D_STATE + n];
    float xv = xc[(size_t)l * D_INNER + d];
    float da = expf(dtv * a);
    s = fmaf(da, s, dtv * bv * xv);
    float part = s * cv;
    part += __shfl_xor(part, 1);
    part += __shfl_xor(part, 2);
    part += __shfl_xor(part, 4);
    part += __shfl_xor(part, 8);
    if (n == 0) ys[(size_t)l * D_INNER + d] = part;
  }
}

// ---------------- y = (ys + xc*D) * silu(z)   [z already silu'd] ----------------
__global__ __launch_bounds__(256) void y_assemble(float* __restrict__ y,
                                                  const float* __restrict__ xc,
                                                  const float* __restrict__ Dskip,
                                                  const float* __restrict__ zs) {
  int idx = blockIdx.x * 256 + threadIdx.x;
  int d = idx & 1023;
  float v = fmaf(xc[idx], Dskip[d], y[idx]);
  y[idx] = v * zs[idx];
}

// ---------------- residual add ----------------
__global__ __launch_bounds__(256) void resid_add(float* __restrict__ h, const float* __restrict__ t) {
  int idx = blockIdx.x * 256 + threadIdx.x;
  h[idx] += t[idx];
}

// ---------------- final head ----------------
__global__ __launch_bounds__(512) void colsum(const float* __restrict__ h, double* __restrict__ part) {
  int d = threadIdx.x;
  int r0 = blockIdx.x * 128;
  double s = 0.0;
  for (int r = 0; r < 128; ++r) s += (double)h[(size_t)(r0 + r) * D_MODEL + d];
  part[blockIdx.x * D_MODEL + d] = s;
}

__global__ __launch_bounds__(512) void head_k(const double* __restrict__ part,
                                              const float* __restrict__ cls_w,
                                              const float* __restrict__ cls_b,
                                              float* __restrict__ out) {
  __shared__ double l0[512], l1[512];
  int d = threadIdx.x;
  double s = 0.0;
  for (int b = 0; b < 32; ++b) s += part[b * D_MODEL + d];
  double hv = s * (1.0 / 4096.0);
  out[d] = (float)hv;
  l0[d] = hv * (double)cls_w[d];
  l1[d] = hv * (double)cls_w[D_MODEL + d];
  __syncthreads();
  for (int o = 256; o > 0; o >>= 1) {
    if (d < o) { l0[d] += l0[d + o]; l1[d] += l1[d + o]; }
    __syncthreads();
  }
  if (d == 0) { out[512] = (float)(l0[0] + (double)cls_b[0]); out[513] = (float)(l1[0] + (double)cls_b[1]); }
}

// ---------------- launch ----------------
extern "C" void kernel_launch(void* const* d_in, const int* in_sizes, int n_in,
                              void* d_out, int out_size, void* d_ws, size_t ws_size,
                              hipStream_t stream) {
  const float* x         = (const float*)d_in[0];
  const float* fc1_w     = (const float*)d_in[1];
  const float* fc1_b     = (const float*)d_in[2];
  const float* ln_w      = (const float*)d_in[3];
  const float* ln_b      = (const float*)d_in[4];
  const float* in_proj_w = (const float*)d_in[5];
  const float* conv_w    = (const float*)d_in[6];
  const float* conv_b    = (const float*)d_in[7];
  const float* x_proj_w  = (const float*)d_in[8];
  const float* dt_proj_w = (const float*)d_in[9];
  const float* dt_proj_b = (const float*)d_in[10];
  const float* A_log     = (const float*)d_in[11];
  const float* D_skip    = (const float*)d_in[12];
  const float* norm_w    = (const float*)d_in[13];
  const float* norm_b    = (const float*)d_in[14];
  const float* cls_w     = (const float*)d_in[15];
  const float* cls_b     = (const float*)d_in[16];
  float* out = (float*)d_out;
  float* ws  = (float*)d_ws;

  float* h_buf   = ws + OFF_H;
  float* hn_buf  = ws + OFF_HN;
  float* P_buf   = ws + OFF_HN;            // overlays hn
  float* carry_b = ws + OFF_HN + 1048576;
  float* temp    = ws + OFF_HN;            // resid temp (P/carry dead by then)
  float* y_buf   = ws + OFF_XCRAW;         // xcraw, later ys -> y
  float* z_buf   = ws + OFF_Z;
  float* xc_buf  = ws + OFF_XC;
  float* dt_buf  = ws + OFF_DT;
  float* dbc_buf = ws + OFF_DBC;
  float* S_buf   = ws + OFF_S;
  float* wout    = ws + OFF_WOUT;
  double* part   = (double*)(ws + OFF_PART);

  gen_wout<<<4096, 256, 0, stream>>>(wout);

  // h = gelu(x @ fc1_w^T + fc1_b)
  gemm_abt<EPI_BIAS_GELU><<<dim3(8, 64), 256, 0, stream>>>(
      x, IN_DIM, fc1_w, IN_DIM, h_buf, D_MODEL, IN_DIM, fc1_b);

  for (int i = 0; i < 2; ++i) {
    const float* Wi = in_proj_w + (size_t)i * 2 * D_INNER * D_MODEL;
    // hn = LN(h)
    ln_rows<<<4096, 256, 0, stream>>>(h_buf, ln_w + i * D_MODEL, ln_b + i * D_MODEL, hn_buf);
    // xcraw = hn @ Wi[0:1024]^T ; zraw = hn @ Wi[1024:2048]^T
    gemm_abt<EPI_NONE><<<dim3(16, 64), 256, 0, stream>>>(
        hn_buf, D_MODEL, Wi, D_MODEL, y_buf /*=xcraw*/, D_INNER, D_MODEL, nullptr);
    gemm_abt<EPI_NONE><<<dim3(16, 64), 256, 0, stream>>>(
        hn_buf, D_MODEL, Wi + (size_t)D_INNER * D_MODEL, D_MODEL, z_buf, D_INNER, D_MODEL, nullptr);
    // z = silu(zraw)
    silu_inplace<<<16384, 256, 0, stream>>>(z_buf);
    // xc = silu(conv(xcraw) + conv_b)
    conv_silu2<<<4096, 256, 0, stream>>>(y_buf, conv_w + (size_t)i * D_INNER * 4,
                                         conv_b + i * D_INNER, xc_buf);
    // dbc = xc @ x_proj_w^T
    gemm_abt<EPI_NONE><<<dim3(1, 64), 256, 0, stream>>>(
        xc_buf, D_INNER, x_proj_w + (size_t)i * 64 * D_INNER, D_INNER,
        dbc_buf, 64, D_INNER, nullptr);
    // dt = softplus(dbc[:, :32] @ dt_proj_w^T + dt_proj_b)
    gemm_abt<EPI_SOFTPLUS><<<dim3(16, 64), 256, 0, stream>>>(
        dbc_buf, 64, dt_proj_w + (size_t)i * D_INNER * DT_RANK, DT_RANK,
        dt_buf, D_INNER, DT_RANK, dt_proj_b + i * D_INNER);
    // selective scan -> ys (into y_buf; xcraw dead after conv)
    const float* Alog_i = A_log + (size_t)i * D_INNER * D_STATE;
    scanA<<<dim3(64, NCHUNK), 256, 0, stream>>>(dt_buf, dbc_buf, xc_buf, Alog_i, P_buf, S_buf);
    scanB<<<64, 256, 0, stream>>>(P_buf, S_buf, carry_b);
    scanC2<<<dim3(64, NCHUNK), 256, 0, stream>>>(dt_buf, dbc_buf, xc_buf, Alog_i, carry_b, y_buf);
    // y = (ys + xc*D) * silu(z)
    y_assemble<<<16384, 256, 0, stream>>>(y_buf, xc_buf, D_skip + i * D_INNER, z_buf);
    // temp = y @ wout^T ; h += temp
    gemm_abt<EPI_NONE><<<dim3(8, 64), 256, 0, stream>>>(
        y_buf, D_INNER, wout + (size_t)i * D_MODEL * D_INNER, D_INNER,
        temp, D_MODEL, D_INNER, nullptr);
    resid_add<<<8192, 256, 0, stream>>>(h_buf, temp);
  }

  ln_rows<<<4096, 256, 0, stream>>>(h_buf, norm_w, norm_b, out + 514);
  colsum<<<32, 512, 0, stream>>>(out + 514, part);
  head_k<<<1, 512, 0, stream>>>(part, cls_w, cls_b, out);
}

// Round 5
// 635.218 us; speedup vs baseline: 2.2368x; 2.2368x over previous
//
#include <hip/hip_runtime.h>
#include <cstdint>
#include <cstddef>

// ---------------- constants ----------------
#define SEQ     4096
#define IN_DIM  1024
#define D_MODEL 512
#define D_INNER 1024
#define D_STATE 16
#define DT_RANK 32

#define CHUNK   64
#define NCHUNK  64     // SEQ / CHUNK
#define NREC    16384  // D_INNER * D_STATE

// workspace layout (float offsets) -- identical footprint to rounds 1-4 (known-safe)
static const size_t OFF_H     = 0;                      // 4096*512
static const size_t OFF_HN    = 2097152;                // hn; P(+0)/carry(+1048576)
static const size_t OFF_XCRAW = 4194304;                // xcraw, later y
static const size_t OFF_Z     = 8388608;                // silu(z) (written by in_proj epilogue)
static const size_t OFF_XC    = 12582912;               // xc (post conv+silu)
static const size_t OFF_DT    = 16777216;               // dt
static const size_t OFF_DBC   = 20971520;               // 4096*64
static const size_t OFF_S     = OFF_DBC + 262144;
static const size_t OFF_WOUT  = OFF_S + 1048576;
static const size_t OFF_PART  = OFF_WOUT + 1048576;

typedef __attribute__((ext_vector_type(8))) short bf16x8;
typedef __attribute__((ext_vector_type(4))) float f32x4;

// ---------------- jax threefry / normal reproduction (VALIDATED round 4) ----------------
__device__ __forceinline__ uint32_t rotl32(uint32_t v, int r) { return (v << r) | (v >> (32 - r)); }

__device__ __forceinline__ void threefry2x32(uint32_t k0, uint32_t k1, uint32_t x0, uint32_t x1,
                                             uint32_t& o0, uint32_t& o1) {
  uint32_t ks0 = k0, ks1 = k1, ks2 = k0 ^ k1 ^ 0x1BD11BDAu;
  x0 += ks0; x1 += ks1;
  const int rotA[4] = {13, 15, 26, 6};
  const int rotB[4] = {17, 29, 16, 24};
  uint32_t ks[3] = {ks0, ks1, ks2};
#pragma unroll
  for (int r = 0; r < 5; ++r) {
    const int* rr = (r & 1) ? rotB : rotA;
#pragma unroll
    for (int j = 0; j < 4; ++j) { x0 += x1; x1 = rotl32(x1, rr[j]); x1 ^= x0; }
    x0 += ks[(r + 1) % 3];
    x1 += ks[(r + 2) % 3] + (uint32_t)(r + 1);
  }
  o0 = x0; o1 = x1;
}

__device__ __forceinline__ float erfinv32(float x) {
  float w = -log1pf(-x * x);
  float p;
  if (w < 5.0f) {
    w -= 2.5f;
    p = 2.81022636e-08f;
    p = fmaf(p, w, 3.43273939e-07f);
    p = fmaf(p, w, -3.5233877e-06f);
    p = fmaf(p, w, -4.39150654e-06f);
    p = fmaf(p, w, 0.00021858087f);
    p = fmaf(p, w, -0.00125372503f);
    p = fmaf(p, w, -0.00417768164f);
    p = fmaf(p, w, 0.246640727f);
    p = fmaf(p, w, 1.50140941f);
  } else {
    w = sqrtf(w) - 3.0f;
    p = -0.000200214257f;
    p = fmaf(p, w, 0.000100950558f);
    p = fmaf(p, w, 0.00134934322f);
    p = fmaf(p, w, -0.00367342844f);
    p = fmaf(p, w, 0.00573950773f);
    p = fmaf(p, w, -0.0076224613f);
    p = fmaf(p, w, 0.00943887047f);
    p = fmaf(p, w, 1.00167406f);
    p = fmaf(p, w, 2.83297682f);
  }
  return p * x;
}

__device__ __forceinline__ float bits_to_normal(uint32_t b) {
  float f = __uint_as_float((b >> 9) | 0x3f800000u) - 1.0f;
  const float lo = -0.99999994f;
  float u = f * (1.0f - lo) + lo;
  u = fmaxf(lo, u);
  return 1.41421356f * erfinv32(u);
}

// PARTITIONABLE threefry bits: bits[j] = o0 ^ o1, counts64 = j (hi=0, lo=j)
__global__ __launch_bounds__(256) void gen_wout(float* __restrict__ w) {
  int gid = blockIdx.x * 256 + threadIdx.x;        // [0, 2*524288)
  int layer = gid >> 19;
  int j = gid & 0x7FFFF;
  uint32_t k0, k1;
  threefry2x32(0u, 7u, 0u, (uint32_t)layer, k0, k1);   // fold_in(key(7), layer)
  uint32_t o0, o1;
  threefry2x32(k0, k1, 0u, (uint32_t)j, o0, o1);
  w[(size_t)layer * 524288 + j] = bits_to_normal(o0 ^ o1) * 0.02f;
}

// ---------------- activations (f32) ----------------
__device__ __forceinline__ float silu_f(float v) { return v / (1.0f + expf(-v)); }
__device__ __forceinline__ float gelu_f(float v) {
  float v3 = v * v * v;
  return 0.5f * v * (1.0f + tanhf(0.7978845608028654f * (v + 0.044715f * v3)));
}
__device__ __forceinline__ float softplus_f(float v) {
  return fmaxf(v, 0.0f) + log1pf(expf(-fabsf(v)));
}

// ---------------- bf16 conversion (RNE) ----------------
__device__ __forceinline__ short f2bf(float x) {
  uint32_t u = __float_as_uint(x);
  u = (u + 0x7FFFu + ((u >> 16) & 1u)) >> 16;
  return (short)u;
}
__device__ __forceinline__ bf16x8 pack8(float4 a, float4 b) {
  bf16x8 v;
  v[0] = f2bf(a.x); v[1] = f2bf(a.y); v[2] = f2bf(a.z); v[3] = f2bf(a.w);
  v[4] = f2bf(b.x); v[5] = f2bf(b.y); v[6] = f2bf(b.z); v[7] = f2bf(b.w);
  return v;
}

// ---------------- bf16 MFMA GEMM: C[M,N] = A[M,K] * B[N,K]^T (+epilogue) ----------------
// 64x64 tile, BK=32, 256 threads (4 waves), wave w -> rows [w*16, w*16+16).
// C/D mapping (m89-verified): col = lane&15, row = (lane>>4)*4 + reg.
enum { EPI_NONE = 0, EPI_BIAS_GELU = 1, EPI_INPROJ = 2, EPI_SOFTPLUS = 3, EPI_RESID = 4 };

template <int EPI>
__global__ __launch_bounds__(256) void gemm_mfma(
    const float* __restrict__ A, int lda,
    const float* __restrict__ B, int ldb,
    float* __restrict__ C, int ldc, int K,
    const float* __restrict__ bias, float* __restrict__ out2) {
  __shared__ short As[64][40];   // stride 40 bf16 = 80 B (16B-aligned, 2-way banks)
  __shared__ short Bs[64][40];
  const int m0 = blockIdx.y * 64, n0 = blockIdx.x * 64;
  const int tid = threadIdx.x;
  const int row = tid >> 2, seg = tid & 3;       // staging: 64 rows x 4 segs of 8
  const int wid = tid >> 6, lane = tid & 63;
  const int lr = lane & 15, lhi = lane >> 4;
  f32x4 acc[4] = {};
  for (int k0 = 0; k0 < K; k0 += 32) {
    const float* pa = A + (size_t)(m0 + row) * lda + k0 + seg * 8;
    float4 a0 = *(const float4*)pa, a1 = *(const float4*)(pa + 4);
    const float* pb = B + (size_t)(n0 + row) * ldb + k0 + seg * 8;
    float4 b0 = *(const float4*)pb, b1 = *(const float4*)(pb + 4);
    if (k0) __syncthreads();
    *(bf16x8*)&As[row][seg * 8] = pack8(a0, a1);
    *(bf16x8*)&Bs[row][seg * 8] = pack8(b0, b1);
    __syncthreads();
    bf16x8 af = *(const bf16x8*)&As[wid * 16 + lr][lhi * 8];
#pragma unroll
    for (int t = 0; t < 4; ++t) {
      bf16x8 bf = *(const bf16x8*)&Bs[t * 16 + lr][lhi * 8];
      acc[t] = __builtin_amdgcn_mfma_f32_16x16x32_bf16(af, bf, acc[t], 0, 0, 0);
    }
  }
#pragma unroll
  for (int t = 0; t < 4; ++t) {
    const int n = n0 + t * 16 + lr;
#pragma unroll
    for (int r = 0; r < 4; ++r) {
      const int m = m0 + wid * 16 + lhi * 4 + r;
      float v = acc[t][r];
      if (EPI == EPI_NONE) {
        C[(size_t)m * ldc + n] = v;
      } else if (EPI == EPI_BIAS_GELU) {
        v += bias[n];
        C[(size_t)m * ldc + n] = gelu_f(v);
      } else if (EPI == EPI_SOFTPLUS) {
        v += bias[n];
        C[(size_t)m * ldc + n] = softplus_f(v);
      } else if (EPI == EPI_RESID) {
        C[(size_t)m * ldc + n] += v;
      } else if (EPI == EPI_INPROJ) {
        if (n < D_INNER) C[(size_t)m * D_INNER + n] = v;
        else             out2[(size_t)m * D_INNER + (n - D_INNER)] = silu_f(v);
      }
    }
  }
}

// ---------------- layernorm (validated) ----------------
__global__ __launch_bounds__(256) void ln_rows(const float* __restrict__ in,
                                               const float* __restrict__ w,
                                               const float* __restrict__ b,
                                               float* __restrict__ out) {
  __shared__ double red[4];
  const int row = blockIdx.x, t = threadIdx.x;
  const float* r = in + (size_t)row * D_MODEL;
  double x0 = (double)r[t], x1 = (double)r[t + 256];
  double s = x0 + x1;
#pragma unroll
  for (int o = 32; o >= 1; o >>= 1) s += __shfl_down(s, o);
  int wid = t >> 6, lane = t & 63;
  if (lane == 0) red[wid] = s;
  __syncthreads();
  double mu = (red[0] + red[1] + red[2] + red[3]) * (1.0 / 512.0);
  __syncthreads();
  double d0 = x0 - mu, d1 = x1 - mu;
  double v = d0 * d0 + d1 * d1;
#pragma unroll
  for (int o = 32; o >= 1; o >>= 1) v += __shfl_down(v, o);
  if (lane == 0) red[wid] = v;
  __syncthreads();
  double var = (red[0] + red[1] + red[2] + red[3]) * (1.0 / 512.0);
  double rs = rsqrt(var + 1e-5);
  out[(size_t)row * D_MODEL + t]       = (float)(d0 * rs * (double)w[t] + (double)b[t]);
  out[(size_t)row * D_MODEL + t + 256] = (float)(d1 * rs * (double)w[t + 256] + (double)b[t + 256]);
}

// ---------------- causal depthwise conv + bias + silu (validated) ----------------
__global__ __launch_bounds__(256) void conv_silu2(const float* __restrict__ xcr,
                                                  const float* __restrict__ cw,
                                                  const float* __restrict__ cb,
                                                  float* __restrict__ out) {
  const int l = blockIdx.x;
  for (int q = 0; q < 4; ++q) {
    const int d = threadIdx.x + q * 256;
    float acc = cb[d];
#pragma unroll
    for (int k = 0; k < 4; ++k) {
      const int ll = l + k - 3;
      const float xv = (ll >= 0) ? xcr[(size_t)ll * D_INNER + d] : 0.0f;
      acc = fmaf(xv, cw[d * 4 + k], acc);
    }
    out[(size_t)l * D_INNER + d] = acc / (1.0f + expf(-acc));
  }
}

// ---------------- selective scan (3-pass chunked, validated) ----------------
__global__ __launch_bounds__(256) void scanA(const float* __restrict__ dt,
                                             const float* __restrict__ dbc,
                                             const float* __restrict__ xc,
                                             const float* __restrict__ Alog,
                                             float* __restrict__ P, float* __restrict__ S) {
  const int dg = blockIdx.x, c = blockIdx.y;
  const int n = threadIdx.x & 15, dd = threadIdx.x >> 4;
  const int d = dg * 16 + dd;
  const float a = -expf(Alog[d * 16 + n]);
  float p = 1.0f, s = 0.0f;
  const int l0 = c * CHUNK;
  for (int t = 0; t < CHUNK; ++t) {
    int l = l0 + t;
    float dtv = dt[(size_t)l * D_INNER + d];
    float bv = dbc[(size_t)l * 64 + DT_RANK + n];
    float xv = xc[(size_t)l * D_INNER + d];
    float da = expf(dtv * a);
    s = fmaf(da, s, dtv * bv * xv);
    p *= da;
  }
  int idx = c * NREC + d * 16 + n;
  P[idx] = p; S[idx] = s;
}

__global__ __launch_bounds__(256) void scanB(const float* __restrict__ P,
                                             const float* __restrict__ S,
                                             float* __restrict__ carry) {
  int idx = blockIdx.x * 256 + threadIdx.x;
  float cr = 0.0f;
  for (int c = 0; c < NCHUNK; ++c) {
    int k = c * NREC + idx;
    carry[k] = cr;
    cr = fmaf(P[k], cr, S[k]);
  }
}

// fused: y = (sum_n s*C + xc*D) * silu_z   (silu already applied to z)
__global__ __launch_bounds__(256) void scanC(const float* __restrict__ dt,
                                             const float* __restrict__ dbc,
                                             const float* __restrict__ xc,
                                             const float* __restrict__ Alog,
                                             const float* __restrict__ carry,
                                             const float* __restrict__ Dskip,
                                             const float* __restrict__ zs,
                                             float* __restrict__ y) {
  const int dg = blockIdx.x, c = blockIdx.y;
  const int n = threadIdx.x & 15, dd = threadIdx.x >> 4;
  const int d = dg * 16 + dd;
  const float a = -expf(Alog[d * 16 + n]);
  float s = carry[c * NREC + d * 16 + n];
  const float dsk = Dskip[d];
  const int l0 = c * CHUNK;
  for (int t = 0; t < CHUNK; ++t) {
    int l = l0 + t;
    float dtv = dt[(size_t)l * D_INNER + d];
    float bv = dbc[(size_t)l * 64 + DT_RANK + n];
    float cv = dbc[(size_t)l * 64 + DT_RANK + D_STATE + n];
    float xv = xc[(size_t)l * D_INNER + d];
    float da = expf(dtv * a);
    s = fmaf(da, s, dtv * bv * xv);
    float part = s * cv;
    part += __shfl_xor(part, 1);
    part += __shfl_xor(part, 2);
    part += __shfl_xor(part, 4);
    part += __shfl_xor(part, 8);
    if (n == 0) {
      float yv = fmaf(xv, dsk, part);
      y[(size_t)l * D_INNER + d] = yv * zs[(size_t)l * D_INNER + d];
    }
  }
}

// ---------------- final head (validated) ----------------
__global__ __launch_bounds__(512) void colsum(const float* __restrict__ h, double* __restrict__ part) {
  int d = threadIdx.x;
  int r0 = blockIdx.x * 128;
  double s = 0.0;
  for (int r = 0; r < 128; ++r) s += (double)h[(size_t)(r0 + r) * D_MODEL + d];
  part[blockIdx.x * D_MODEL + d] = s;
}

__global__ __launch_bounds__(512) void head_k(const double* __restrict__ part,
                                              const float* __restrict__ cls_w,
                                              const float* __restrict__ cls_b,
                                              float* __restrict__ out) {
  __shared__ double l0[512], l1[512];
  int d = threadIdx.x;
  double s = 0.0;
  for (int b = 0; b < 32; ++b) s += part[b * D_MODEL + d];
  double hv = s * (1.0 / 4096.0);
  out[d] = (float)hv;
  l0[d] = hv * (double)cls_w[d];
  l1[d] = hv * (double)cls_w[D_MODEL + d];
  __syncthreads();
  for (int o = 256; o > 0; o >>= 1) {
    if (d < o) { l0[d] += l0[d + o]; l1[d] += l1[d + o]; }
    __syncthreads();
  }
  if (d == 0) { out[512] = (float)(l0[0] + (double)cls_b[0]); out[513] = (float)(l1[0] + (double)cls_b[1]); }
}

// ---------------- launch ----------------
extern "C" void kernel_launch(void* const* d_in, const int* in_sizes, int n_in,
                              void* d_out, int out_size, void* d_ws, size_t ws_size,
                              hipStream_t stream) {
  const float* x         = (const float*)d_in[0];
  const float* fc1_w     = (const float*)d_in[1];
  const float* fc1_b     = (const float*)d_in[2];
  const float* ln_w      = (const float*)d_in[3];
  const float* ln_b      = (const float*)d_in[4];
  const float* in_proj_w = (const float*)d_in[5];
  const float* conv_w    = (const float*)d_in[6];
  const float* conv_b    = (const float*)d_in[7];
  const float* x_proj_w  = (const float*)d_in[8];
  const float* dt_proj_w = (const float*)d_in[9];
  const float* dt_proj_b = (const float*)d_in[10];
  const float* A_log     = (const float*)d_in[11];
  const float* D_skip    = (const float*)d_in[12];
  const float* norm_w    = (const float*)d_in[13];
  const float* norm_b    = (const float*)d_in[14];
  const float* cls_w     = (const float*)d_in[15];
  const float* cls_b     = (const float*)d_in[16];
  float* out = (float*)d_out;
  float* ws  = (float*)d_ws;

  float* h_buf   = ws + OFF_H;
  float* hn_buf  = ws + OFF_HN;
  float* P_buf   = ws + OFF_HN;            // overlays hn (dead after in_proj)
  float* carry_b = ws + OFF_HN + 1048576;
  float* y_buf   = ws + OFF_XCRAW;         // xcraw, later y
  float* z_buf   = ws + OFF_Z;
  float* xc_buf  = ws + OFF_XC;
  float* dt_buf  = ws + OFF_DT;
  float* dbc_buf = ws + OFF_DBC;
  float* S_buf   = ws + OFF_S;
  float* wout    = ws + OFF_WOUT;
  double* part   = (double*)(ws + OFF_PART);

  gen_wout<<<4096, 256, 0, stream>>>(wout);

  // h = gelu(x @ fc1_w^T + fc1_b)    [4096,512]
  gemm_mfma<EPI_BIAS_GELU><<<dim3(8, 64), 256, 0, stream>>>(
      x, IN_DIM, fc1_w, IN_DIM, h_buf, D_MODEL, IN_DIM, fc1_b, nullptr);

  for (int i = 0; i < 2; ++i) {
    const float* Wi = in_proj_w + (size_t)i * 2 * D_INNER * D_MODEL;
    // hn = LN(h)
    ln_rows<<<4096, 256, 0, stream>>>(h_buf, ln_w + i * D_MODEL, ln_b + i * D_MODEL, hn_buf);
    // xz = hn @ Wi^T -> xcraw (n<1024), silu(z) (n>=1024)
    gemm_mfma<EPI_INPROJ><<<dim3(32, 64), 256, 0, stream>>>(
        hn_buf, D_MODEL, Wi, D_MODEL, y_buf /*=xcraw*/, D_INNER, D_MODEL, nullptr, z_buf);
    // xc = silu(conv(xcraw) + conv_b)
    conv_silu2<<<4096, 256, 0, stream>>>(y_buf, conv_w + (size_t)i * D_INNER * 4,
                                         conv_b + i * D_INNER, xc_buf);
    // dbc = xc @ x_proj_w^T   [4096,64]
    gemm_mfma<EPI_NONE><<<dim3(1, 64), 256, 0, stream>>>(
        xc_buf, D_INNER, x_proj_w + (size_t)i * 64 * D_INNER, D_INNER,
        dbc_buf, 64, D_INNER, nullptr, nullptr);
    // dt = softplus(dbc[:, :32] @ dt_proj_w^T + dt_proj_b)   [4096,1024]
    gemm_mfma<EPI_SOFTPLUS><<<dim3(16, 64), 256, 0, stream>>>(
        dbc_buf, 64, dt_proj_w + (size_t)i * D_INNER * DT_RANK, DT_RANK,
        dt_buf, D_INNER, DT_RANK, dt_proj_b + i * D_INNER, nullptr);
    // selective scan -> y (fused y-assembly)
    const float* Alog_i = A_log + (size_t)i * D_INNER * D_STATE;
    scanA<<<dim3(64, NCHUNK), 256, 0, stream>>>(dt_buf, dbc_buf, xc_buf, Alog_i, P_buf, S_buf);
    scanB<<<64, 256, 0, stream>>>(P_buf, S_buf, carry_b);
    scanC<<<dim3(64, NCHUNK), 256, 0, stream>>>(dt_buf, dbc_buf, xc_buf, Alog_i, carry_b,
                                                D_skip + i * D_INNER, z_buf, y_buf);
    // h += y @ wout^T   (fused residual)
    gemm_mfma<EPI_RESID><<<dim3(8, 64), 256, 0, stream>>>(
        y_buf, D_INNER, wout + (size_t)i * D_MODEL * D_INNER, D_INNER,
        h_buf, D_MODEL, D_INNER, nullptr, nullptr);
  }

  ln_rows<<<4096, 256, 0, stream>>>(h_buf, norm_w, norm_b, out + 514);
  colsum<<<32, 512, 0, stream>>>(out + 514, part);
  head_k<<<1, 512, 0, stream>>>(part, cls_w, cls_b, out);
}

// Round 6
// 600.492 us; speedup vs baseline: 2.3661x; 1.0578x over previous
//
#include <hip/hip_runtime.h>
#include <cstdint>
#include <cstddef>

// ---------------- constants ----------------
#define SEQ     4096
#define IN_DIM  1024
#define D_MODEL 512
#define D_INNER 1024
#define D_STATE 16
#define DT_RANK 32

#define CHUNK   64
#define NCHUNK  64     // SEQ / CHUNK
#define NREC    16384  // D_INNER * D_STATE

#define LOG2E 1.44269504088896f

// workspace layout (float offsets) -- identical footprint to rounds 1-5 (known-safe)
static const size_t OFF_H     = 0;                      // 4096*512
static const size_t OFF_HN    = 2097152;                // hn; P(+0)/carry(+1048576)
static const size_t OFF_XCRAW = 4194304;                // xcraw, later y
static const size_t OFF_Z     = 8388608;                // silu(z) (written by in_proj epilogue)
static const size_t OFF_XC    = 12582912;               // xc (post conv+silu)
static const size_t OFF_DT    = 16777216;               // dt
static const size_t OFF_DBC   = 20971520;               // 4096*64
static const size_t OFF_S     = OFF_DBC + 262144;
static const size_t OFF_WOUT  = OFF_S + 1048576;
static const size_t OFF_PART  = OFF_WOUT + 1048576;

typedef __attribute__((ext_vector_type(8))) short bf16x8;
typedef __attribute__((ext_vector_type(4))) float f32x4;

// ---------------- jax threefry / normal reproduction (VALIDATED round 4) ----------------
__device__ __forceinline__ uint32_t rotl32(uint32_t v, int r) { return (v << r) | (v >> (32 - r)); }

__device__ __forceinline__ void threefry2x32(uint32_t k0, uint32_t k1, uint32_t x0, uint32_t x1,
                                             uint32_t& o0, uint32_t& o1) {
  uint32_t ks0 = k0, ks1 = k1, ks2 = k0 ^ k1 ^ 0x1BD11BDAu;
  x0 += ks0; x1 += ks1;
  const int rotA[4] = {13, 15, 26, 6};
  const int rotB[4] = {17, 29, 16, 24};
  uint32_t ks[3] = {ks0, ks1, ks2};
#pragma unroll
  for (int r = 0; r < 5; ++r) {
    const int* rr = (r & 1) ? rotB : rotA;
#pragma unroll
    for (int j = 0; j < 4; ++j) { x0 += x1; x1 = rotl32(x1, rr[j]); x1 ^= x0; }
    x0 += ks[(r + 1) % 3];
    x1 += ks[(r + 2) % 3] + (uint32_t)(r + 1);
  }
  o0 = x0; o1 = x1;
}

__device__ __forceinline__ float erfinv32(float x) {
  float w = -log1pf(-x * x);
  float p;
  if (w < 5.0f) {
    w -= 2.5f;
    p = 2.81022636e-08f;
    p = fmaf(p, w, 3.43273939e-07f);
    p = fmaf(p, w, -3.5233877e-06f);
    p = fmaf(p, w, -4.39150654e-06f);
    p = fmaf(p, w, 0.00021858087f);
    p = fmaf(p, w, -0.00125372503f);
    p = fmaf(p, w, -0.00417768164f);
    p = fmaf(p, w, 0.246640727f);
    p = fmaf(p, w, 1.50140941f);
  } else {
    w = sqrtf(w) - 3.0f;
    p = -0.000200214257f;
    p = fmaf(p, w, 0.000100950558f);
    p = fmaf(p, w, 0.00134934322f);
    p = fmaf(p, w, -0.00367342844f);
    p = fmaf(p, w, 0.00573950773f);
    p = fmaf(p, w, -0.0076224613f);
    p = fmaf(p, w, 0.00943887047f);
    p = fmaf(p, w, 1.00167406f);
    p = fmaf(p, w, 2.83297682f);
  }
  return p * x;
}

__device__ __forceinline__ float bits_to_normal(uint32_t b) {
  float f = __uint_as_float((b >> 9) | 0x3f800000u) - 1.0f;
  const float lo = -0.99999994f;
  float u = f * (1.0f - lo) + lo;
  u = fmaxf(lo, u);
  return 1.41421356f * erfinv32(u);
}

// PARTITIONABLE threefry bits: bits[j] = o0 ^ o1, counts64 = j (hi=0, lo=j)
__global__ __launch_bounds__(256) void gen_wout(float* __restrict__ w) {
  int gid = blockIdx.x * 256 + threadIdx.x;        // [0, 2*524288)
  int layer = gid >> 19;
  int j = gid & 0x7FFFF;
  uint32_t k0, k1;
  threefry2x32(0u, 7u, 0u, (uint32_t)layer, k0, k1);   // fold_in(key(7), layer)
  uint32_t o0, o1;
  threefry2x32(k0, k1, 0u, (uint32_t)j, o0, o1);
  w[(size_t)layer * 524288 + j] = bits_to_normal(o0 ^ o1) * 0.02f;
}

// ---------------- activations (exp2-based fast forms) ----------------
__device__ __forceinline__ float silu_f(float v) { return v / (1.0f + exp2f(-LOG2E * v)); }
__device__ __forceinline__ float gelu_f(float v) {
  float v3 = v * v * v;
  return 0.5f * v * (1.0f + tanhf(0.7978845608028654f * (v + 0.044715f * v3)));
}
__device__ __forceinline__ float softplus_f(float v) {
  return fmaxf(v, 0.0f) + log1pf(exp2f(-LOG2E * fabsf(v)));
}

// ---------------- 16-lane sum reduce via DPP row_ror (no LDS pipe) ----------------
__device__ __forceinline__ float red16(float v) {
  v += __int_as_float(__builtin_amdgcn_update_dpp(0, __float_as_int(v), 0x128, 0xF, 0xF, false)); // ror:8
  v += __int_as_float(__builtin_amdgcn_update_dpp(0, __float_as_int(v), 0x124, 0xF, 0xF, false)); // ror:4
  v += __int_as_float(__builtin_amdgcn_update_dpp(0, __float_as_int(v), 0x122, 0xF, 0xF, false)); // ror:2
  v += __int_as_float(__builtin_amdgcn_update_dpp(0, __float_as_int(v), 0x121, 0xF, 0xF, false)); // ror:1
  return v;
}

// ---------------- bf16 conversion (RNE) ----------------
__device__ __forceinline__ short f2bf(float x) {
  uint32_t u = __float_as_uint(x);
  u = (u + 0x7FFFu + ((u >> 16) & 1u)) >> 16;
  return (short)u;
}
__device__ __forceinline__ bf16x8 pack8(float4 a, float4 b) {
  bf16x8 v;
  v[0] = f2bf(a.x); v[1] = f2bf(a.y); v[2] = f2bf(a.z); v[3] = f2bf(a.w);
  v[4] = f2bf(b.x); v[5] = f2bf(b.y); v[6] = f2bf(b.z); v[7] = f2bf(b.w);
  return v;
}

// ---------------- bf16 MFMA GEMM: C[M,N] = A[M,K] * B[N,K]^T (+epilogue) ----------------
// 64x64 tile, BK=32, 256 threads (4 waves). C/D map (m89): col=lane&15, row=(lane>>4)*4+reg.
enum { EPI_NONE = 0, EPI_BIAS_GELU = 1, EPI_INPROJ = 2, EPI_SOFTPLUS = 3, EPI_RESID = 4 };

template <int EPI>
__global__ __launch_bounds__(256) void gemm_mfma(
    const float* __restrict__ A, int lda,
    const float* __restrict__ B, int ldb,
    float* __restrict__ C, int ldc, int K,
    const float* __restrict__ bias, float* __restrict__ out2) {
  __shared__ short As[64][40];
  __shared__ short Bs[64][40];
  const int m0 = blockIdx.y * 64, n0 = blockIdx.x * 64;
  const int tid = threadIdx.x;
  const int row = tid >> 2, seg = tid & 3;
  const int wid = tid >> 6, lane = tid & 63;
  const int lr = lane & 15, lhi = lane >> 4;
  f32x4 acc[4] = {};
  for (int k0 = 0; k0 < K; k0 += 32) {
    const float* pa = A + (size_t)(m0 + row) * lda + k0 + seg * 8;
    float4 a0 = *(const float4*)pa, a1 = *(const float4*)(pa + 4);
    const float* pb = B + (size_t)(n0 + row) * ldb + k0 + seg * 8;
    float4 b0 = *(const float4*)pb, b1 = *(const float4*)(pb + 4);
    if (k0) __syncthreads();
    *(bf16x8*)&As[row][seg * 8] = pack8(a0, a1);
    *(bf16x8*)&Bs[row][seg * 8] = pack8(b0, b1);
    __syncthreads();
    bf16x8 af = *(const bf16x8*)&As[wid * 16 + lr][lhi * 8];
#pragma unroll
    for (int t = 0; t < 4; ++t) {
      bf16x8 bf = *(const bf16x8*)&Bs[t * 16 + lr][lhi * 8];
      acc[t] = __builtin_amdgcn_mfma_f32_16x16x32_bf16(af, bf, acc[t], 0, 0, 0);
    }
  }
#pragma unroll
  for (int t = 0; t < 4; ++t) {
    const int n = n0 + t * 16 + lr;
#pragma unroll
    for (int r = 0; r < 4; ++r) {
      const int m = m0 + wid * 16 + lhi * 4 + r;
      float v = acc[t][r];
      if (EPI == EPI_NONE) {
        C[(size_t)m * ldc + n] = v;
      } else if (EPI == EPI_BIAS_GELU) {
        v += bias[n];
        C[(size_t)m * ldc + n] = gelu_f(v);
      } else if (EPI == EPI_SOFTPLUS) {
        v += bias[n];
        C[(size_t)m * ldc + n] = softplus_f(v);
      } else if (EPI == EPI_RESID) {
        C[(size_t)m * ldc + n] += v;
      } else if (EPI == EPI_INPROJ) {
        if (n < D_INNER) C[(size_t)m * D_INNER + n] = v;
        else             out2[(size_t)m * D_INNER + (n - D_INNER)] = silu_f(v);
      }
    }
  }
}

// ---------------- layernorm (validated) ----------------
__global__ __launch_bounds__(256) void ln_rows(const float* __restrict__ in,
                                               const float* __restrict__ w,
                                               const float* __restrict__ b,
                                               float* __restrict__ out) {
  __shared__ double red[4];
  const int row = blockIdx.x, t = threadIdx.x;
  const float* r = in + (size_t)row * D_MODEL;
  double x0 = (double)r[t], x1 = (double)r[t + 256];
  double s = x0 + x1;
#pragma unroll
  for (int o = 32; o >= 1; o >>= 1) s += __shfl_down(s, o);
  int wid = t >> 6, lane = t & 63;
  if (lane == 0) red[wid] = s;
  __syncthreads();
  double mu = (red[0] + red[1] + red[2] + red[3]) * (1.0 / 512.0);
  __syncthreads();
  double d0 = x0 - mu, d1 = x1 - mu;
  double v = d0 * d0 + d1 * d1;
#pragma unroll
  for (int o = 32; o >= 1; o >>= 1) v += __shfl_down(v, o);
  if (lane == 0) red[wid] = v;
  __syncthreads();
  double var = (red[0] + red[1] + red[2] + red[3]) * (1.0 / 512.0);
  double rs = rsqrt(var + 1e-5);
  out[(size_t)row * D_MODEL + t]       = (float)(d0 * rs * (double)w[t] + (double)b[t]);
  out[(size_t)row * D_MODEL + t + 256] = (float)(d1 * rs * (double)w[t + 256] + (double)b[t + 256]);
}

// ---------------- causal depthwise conv + bias + silu ----------------
__global__ __launch_bounds__(256) void conv_silu2(const float* __restrict__ xcr,
                                                  const float* __restrict__ cw,
                                                  const float* __restrict__ cb,
                                                  float* __restrict__ out) {
  const int l = blockIdx.x;
  for (int q = 0; q < 4; ++q) {
    const int d = threadIdx.x + q * 256;
    float acc = cb[d];
#pragma unroll
    for (int k = 0; k < 4; ++k) {
      const int ll = l + k - 3;
      const float xv = (ll >= 0) ? xcr[(size_t)ll * D_INNER + d] : 0.0f;
      acc = fmaf(xv, cw[d * 4 + k], acc);
    }
    out[(size_t)l * D_INNER + d] = silu_f(acc);
  }
}

// ---------------- selective scan (3-pass chunked) ----------------
// exp(dt*a) = exp2(dt * a2) with a2 = a*log2(e); chunk product = exp2(a2 * sum(dt)).
__global__ __launch_bounds__(256) void scanA(const float* __restrict__ dt,
                                             const float* __restrict__ dbc,
                                             const float* __restrict__ xc,
                                             const float* __restrict__ Alog,
                                             float* __restrict__ P, float* __restrict__ S) {
  const int dg = blockIdx.x, c = blockIdx.y;
  const int n = threadIdx.x & 15, dd = threadIdx.x >> 4;
  const int d = dg * 16 + dd;
  const float a2 = -expf(Alog[d * 16 + n]) * LOG2E;
  float sdt = 0.0f, s = 0.0f;
  const int l0 = c * CHUNK;
#pragma unroll 8
  for (int t = 0; t < CHUNK; ++t) {
    int l = l0 + t;
    float dtv = dt[(size_t)l * D_INNER + d];
    float bv = dbc[(size_t)l * 64 + DT_RANK + n];
    float xv = xc[(size_t)l * D_INNER + d];
    float da = exp2f(dtv * a2);
    s = fmaf(da, s, dtv * bv * xv);
    sdt += dtv;
  }
  int idx = c * NREC + d * 16 + n;
  P[idx] = exp2f(a2 * sdt); S[idx] = s;
}

__global__ __launch_bounds__(256) void scanB(const float* __restrict__ P,
                                             const float* __restrict__ S,
                                             float* __restrict__ carry) {
  int idx = blockIdx.x * 256 + threadIdx.x;
  float cr = 0.0f;
  for (int c = 0; c < NCHUNK; ++c) {
    int k = c * NREC + idx;
    carry[k] = cr;
    cr = fmaf(P[k], cr, S[k]);
  }
}

// fused: y = (sum_n s*C + xc*D) * silu_z ; reduction over n via DPP (no LDS pipe)
__global__ __launch_bounds__(256) void scanC(const float* __restrict__ dt,
                                             const float* __restrict__ dbc,
                                             const float* __restrict__ xc,
                                             const float* __restrict__ Alog,
                                             const float* __restrict__ carry,
                                             const float* __restrict__ Dskip,
                                             const float* __restrict__ zs,
                                             float* __restrict__ y) {
  const int dg = blockIdx.x, c = blockIdx.y;
  const int n = threadIdx.x & 15, dd = threadIdx.x >> 4;
  const int d = dg * 16 + dd;
  const float a2 = -expf(Alog[d * 16 + n]) * LOG2E;
  float s = carry[c * NREC + d * 16 + n];
  const float dsk = Dskip[d];
  const int l0 = c * CHUNK;
#pragma unroll 8
  for (int t = 0; t < CHUNK; ++t) {
    int l = l0 + t;
    float dtv = dt[(size_t)l * D_INNER + d];
    float bv = dbc[(size_t)l * 64 + DT_RANK + n];
    float cv = dbc[(size_t)l * 64 + DT_RANK + D_STATE + n];
    float xv = xc[(size_t)l * D_INNER + d];
    float da = exp2f(dtv * a2);
    s = fmaf(da, s, dtv * bv * xv);
    float tot = red16(s * cv);
    if (n == 0) {
      float yv = fmaf(xv, dsk, tot);
      y[(size_t)l * D_INNER + d] = yv * zs[(size_t)l * D_INNER + d];
    }
  }
}

// ---------------- final head (validated) ----------------
__global__ __launch_bounds__(512) void colsum(const float* __restrict__ h, double* __restrict__ part) {
  int d = threadIdx.x;
  int r0 = blockIdx.x * 128;
  double s = 0.0;
  for (int r = 0; r < 128; ++r) s += (double)h[(size_t)(r0 + r) * D_MODEL + d];
  part[blockIdx.x * D_MODEL + d] = s;
}

__global__ __launch_bounds__(512) void head_k(const double* __restrict__ part,
                                              const float* __restrict__ cls_w,
                                              const float* __restrict__ cls_b,
                                              float* __restrict__ out) {
  __shared__ double l0[512], l1[512];
  int d = threadIdx.x;
  double s = 0.0;
  for (int b = 0; b < 32; ++b) s += part[b * D_MODEL + d];
  double hv = s * (1.0 / 4096.0);
  out[d] = (float)hv;
  l0[d] = hv * (double)cls_w[d];
  l1[d] = hv * (double)cls_w[D_MODEL + d];
  __syncthreads();
  for (int o = 256; o > 0; o >>= 1) {
    if (d < o) { l0[d] += l0[d + o]; l1[d] += l1[d + o]; }
    __syncthreads();
  }
  if (d == 0) { out[512] = (float)(l0[0] + (double)cls_b[0]); out[513] = (float)(l1[0] + (double)cls_b[1]); }
}

// ---------------- launch ----------------
extern "C" void kernel_launch(void* const* d_in, const int* in_sizes, int n_in,
                              void* d_out, int out_size, void* d_ws, size_t ws_size,
                              hipStream_t stream) {
  const float* x         = (const float*)d_in[0];
  const float* fc1_w     = (const float*)d_in[1];
  const float* fc1_b     = (const float*)d_in[2];
  const float* ln_w      = (const float*)d_in[3];
  const float* ln_b      = (const float*)d_in[4];
  const float* in_proj_w = (const float*)d_in[5];
  const float* conv_w    = (const float*)d_in[6];
  const float* conv_b    = (const float*)d_in[7];
  const float* x_proj_w  = (const float*)d_in[8];
  const float* dt_proj_w = (const float*)d_in[9];
  const float* dt_proj_b = (const float*)d_in[10];
  const float* A_log     = (const float*)d_in[11];
  const float* D_skip    = (const float*)d_in[12];
  const float* norm_w    = (const float*)d_in[13];
  const float* norm_b    = (const float*)d_in[14];
  const float* cls_w     = (const float*)d_in[15];
  const float* cls_b     = (const float*)d_in[16];
  float* out = (float*)d_out;
  float* ws  = (float*)d_ws;

  float* h_buf   = ws + OFF_H;
  float* hn_buf  = ws + OFF_HN;
  float* P_buf   = ws + OFF_HN;            // overlays hn (dead after in_proj)
  float* carry_b = ws + OFF_HN + 1048576;
  float* y_buf   = ws + OFF_XCRAW;         // xcraw, later y
  float* z_buf   = ws + OFF_Z;
  float* xc_buf  = ws + OFF_XC;
  float* dt_buf  = ws + OFF_DT;
  float* dbc_buf = ws + OFF_DBC;
  float* S_buf   = ws + OFF_S;
  float* wout    = ws + OFF_WOUT;
  double* part   = (double*)(ws + OFF_PART);

  gen_wout<<<4096, 256, 0, stream>>>(wout);

  // h = gelu(x @ fc1_w^T + fc1_b)    [4096,512]
  gemm_mfma<EPI_BIAS_GELU><<<dim3(8, 64), 256, 0, stream>>>(
      x, IN_DIM, fc1_w, IN_DIM, h_buf, D_MODEL, IN_DIM, fc1_b, nullptr);

  for (int i = 0; i < 2; ++i) {
    const float* Wi = in_proj_w + (size_t)i * 2 * D_INNER * D_MODEL;
    // hn = LN(h)
    ln_rows<<<4096, 256, 0, stream>>>(h_buf, ln_w + i * D_MODEL, ln_b + i * D_MODEL, hn_buf);
    // xz = hn @ Wi^T -> xcraw (n<1024), silu(z) (n>=1024)
    gemm_mfma<EPI_INPROJ><<<dim3(32, 64), 256, 0, stream>>>(
        hn_buf, D_MODEL, Wi, D_MODEL, y_buf /*=xcraw*/, D_INNER, D_MODEL, nullptr, z_buf);
    // xc = silu(conv(xcraw) + conv_b)
    conv_silu2<<<4096, 256, 0, stream>>>(y_buf, conv_w + (size_t)i * D_INNER * 4,
                                         conv_b + i * D_INNER, xc_buf);
    // dbc = xc @ x_proj_w^T   [4096,64]
    gemm_mfma<EPI_NONE><<<dim3(1, 64), 256, 0, stream>>>(
        xc_buf, D_INNER, x_proj_w + (size_t)i * 64 * D_INNER, D_INNER,
        dbc_buf, 64, D_INNER, nullptr, nullptr);
    // dt = softplus(dbc[:, :32] @ dt_proj_w^T + dt_proj_b)   [4096,1024]
    gemm_mfma<EPI_SOFTPLUS><<<dim3(16, 64), 256, 0, stream>>>(
        dbc_buf, 64, dt_proj_w + (size_t)i * D_INNER * DT_RANK, DT_RANK,
        dt_buf, D_INNER, DT_RANK, dt_proj_b + i * D_INNER, nullptr);
    // selective scan -> y (fused y-assembly)
    const float* Alog_i = A_log + (size_t)i * D_INNER * D_STATE;
    scanA<<<dim3(64, NCHUNK), 256, 0, stream>>>(dt_buf, dbc_buf, xc_buf, Alog_i, P_buf, S_buf);
    scanB<<<64, 256, 0, stream>>>(P_buf, S_buf, carry_b);
    scanC<<<dim3(64, NCHUNK), 256, 0, stream>>>(dt_buf, dbc_buf, xc_buf, Alog_i, carry_b,
                                                D_skip + i * D_INNER, z_buf, y_buf);
    // h += y @ wout^T   (fused residual)
    gemm_mfma<EPI_RESID><<<dim3(8, 64), 256, 0, stream>>>(
        y_buf, D_INNER, wout + (size_t)i * D_MODEL * D_INNER, D_INNER,
        h_buf, D_MODEL, D_INNER, nullptr, nullptr);
  }

  ln_rows<<<4096, 256, 0, stream>>>(h_buf, norm_w, norm_b, out + 514);
  colsum<<<32, 512, 0, stream>>>(out + 514, part);
  head_k<<<1, 512, 0, stream>>>(part, cls_w, cls_b, out);
}

// Round 7
// 476.004 us; speedup vs baseline: 2.9849x; 1.2615x over previous
//
#include <hip/hip_runtime.h>
#include <cstdint>
#include <cstddef>

// ---------------- constants ----------------
#define SEQ     4096
#define IN_DIM  1024
#define D_MODEL 512
#define D_INNER 1024
#define D_STATE 16
#define DT_RANK 32

#define CHUNK   32
#define NCHUNK  128    // SEQ / CHUNK
#define NREC    16384  // D_INNER * D_STATE

#define LOG2E 1.44269504088896f

// workspace layout (float offsets)
// OFF_HN: hn (LN out) -> dead after in_proj -> carry (2M)
// OFF_XCRAW: xcraw -> dead after conv -> P (2M) + S (2M) -> dead after scanB -> y (4M)
static const size_t OFF_H     = 0;                       // 4096*512 = 2M
static const size_t OFF_HN    = 2097152;                 // 2M
static const size_t OFF_XCRAW = 4194304;                 // 4M
static const size_t OFF_Z     = 8388608;                 // 4M
static const size_t OFF_XC    = 12582912;                // 4M
static const size_t OFF_DT    = 16777216;                // 4M
static const size_t OFF_DBC   = 20971520;                // 4096*64 = 256K
static const size_t OFF_WOUT  = OFF_DBC + 262144;        // 1M
static const size_t OFF_PART  = OFF_WOUT + 1048576;      // 32*512 doubles
// high-water ~ 22.3M floats ~ 89.3 MB (within proven-safe 93.5 MB)

typedef __attribute__((ext_vector_type(8))) short bf16x8;
typedef __attribute__((ext_vector_type(4))) float f32x4;

// ---------------- jax threefry / normal reproduction (VALIDATED round 4) ----------------
__device__ __forceinline__ uint32_t rotl32(uint32_t v, int r) { return (v << r) | (v >> (32 - r)); }

__device__ __forceinline__ void threefry2x32(uint32_t k0, uint32_t k1, uint32_t x0, uint32_t x1,
                                             uint32_t& o0, uint32_t& o1) {
  uint32_t ks0 = k0, ks1 = k1, ks2 = k0 ^ k1 ^ 0x1BD11BDAu;
  x0 += ks0; x1 += ks1;
  const int rotA[4] = {13, 15, 26, 6};
  const int rotB[4] = {17, 29, 16, 24};
  uint32_t ks[3] = {ks0, ks1, ks2};
#pragma unroll
  for (int r = 0; r < 5; ++r) {
    const int* rr = (r & 1) ? rotB : rotA;
#pragma unroll
    for (int j = 0; j < 4; ++j) { x0 += x1; x1 = rotl32(x1, rr[j]); x1 ^= x0; }
    x0 += ks[(r + 1) % 3];
    x1 += ks[(r + 2) % 3] + (uint32_t)(r + 1);
  }
  o0 = x0; o1 = x1;
}

__device__ __forceinline__ float erfinv32(float x) {
  float w = -log1pf(-x * x);
  float p;
  if (w < 5.0f) {
    w -= 2.5f;
    p = 2.81022636e-08f;
    p = fmaf(p, w, 3.43273939e-07f);
    p = fmaf(p, w, -3.5233877e-06f);
    p = fmaf(p, w, -4.39150654e-06f);
    p = fmaf(p, w, 0.00021858087f);
    p = fmaf(p, w, -0.00125372503f);
    p = fmaf(p, w, -0.00417768164f);
    p = fmaf(p, w, 0.246640727f);
    p = fmaf(p, w, 1.50140941f);
  } else {
    w = sqrtf(w) - 3.0f;
    p = -0.000200214257f;
    p = fmaf(p, w, 0.000100950558f);
    p = fmaf(p, w, 0.00134934322f);
    p = fmaf(p, w, -0.00367342844f);
    p = fmaf(p, w, 0.00573950773f);
    p = fmaf(p, w, -0.0076224613f);
    p = fmaf(p, w, 0.00943887047f);
    p = fmaf(p, w, 1.00167406f);
    p = fmaf(p, w, 2.83297682f);
  }
  return p * x;
}

__device__ __forceinline__ float bits_to_normal(uint32_t b) {
  float f = __uint_as_float((b >> 9) | 0x3f800000u) - 1.0f;
  const float lo = -0.99999994f;
  float u = f * (1.0f - lo) + lo;
  u = fmaxf(lo, u);
  return 1.41421356f * erfinv32(u);
}

// PARTITIONABLE threefry bits: bits[j] = o0 ^ o1, counts64 = j (hi=0, lo=j)
__global__ __launch_bounds__(256) void gen_wout(float* __restrict__ w) {
  int gid = blockIdx.x * 256 + threadIdx.x;        // [0, 2*524288)
  int layer = gid >> 19;
  int j = gid & 0x7FFFF;
  uint32_t k0, k1;
  threefry2x32(0u, 7u, 0u, (uint32_t)layer, k0, k1);   // fold_in(key(7), layer)
  uint32_t o0, o1;
  threefry2x32(k0, k1, 0u, (uint32_t)j, o0, o1);
  w[(size_t)layer * 524288 + j] = bits_to_normal(o0 ^ o1) * 0.02f;
}

// ---------------- activations (exp2-based fast forms) ----------------
__device__ __forceinline__ float silu_f(float v) { return v / (1.0f + exp2f(-LOG2E * v)); }
__device__ __forceinline__ float gelu_f(float v) {
  float v3 = v * v * v;
  return 0.5f * v * (1.0f + tanhf(0.7978845608028654f * (v + 0.044715f * v3)));
}
__device__ __forceinline__ float softplus_f(float v) {
  return fmaxf(v, 0.0f) + log1pf(exp2f(-LOG2E * fabsf(v)));
}

// ---------------- bf16 conversion (RNE) ----------------
__device__ __forceinline__ short f2bf(float x) {
  uint32_t u = __float_as_uint(x);
  u = (u + 0x7FFFu + ((u >> 16) & 1u)) >> 16;
  return (short)u;
}
__device__ __forceinline__ bf16x8 pack8(float4 a, float4 b) {
  bf16x8 v;
  v[0] = f2bf(a.x); v[1] = f2bf(a.y); v[2] = f2bf(a.z); v[3] = f2bf(a.w);
  v[4] = f2bf(b.x); v[5] = f2bf(b.y); v[6] = f2bf(b.z); v[7] = f2bf(b.w);
  return v;
}

// ---------------- bf16 MFMA GEMM: C[M,N] = A[M,K] * B[N,K]^T (+epilogue) ----------------
// 64x64 tile, BK=32, 256 threads (4 waves). C/D map (m89): col=lane&15, row=(lane>>4)*4+reg.
enum { EPI_NONE = 0, EPI_BIAS_GELU = 1, EPI_INPROJ = 2, EPI_SOFTPLUS = 3, EPI_RESID = 4 };

template <int EPI>
__global__ __launch_bounds__(256) void gemm_mfma(
    const float* __restrict__ A, int lda,
    const float* __restrict__ B, int ldb,
    float* __restrict__ C, int ldc, int K,
    const float* __restrict__ bias, float* __restrict__ out2) {
  __shared__ short As[64][40];
  __shared__ short Bs[64][40];
  const int m0 = blockIdx.y * 64, n0 = blockIdx.x * 64;
  const int tid = threadIdx.x;
  const int row = tid >> 2, seg = tid & 3;
  const int wid = tid >> 6, lane = tid & 63;
  const int lr = lane & 15, lhi = lane >> 4;
  f32x4 acc[4] = {};
  for (int k0 = 0; k0 < K; k0 += 32) {
    const float* pa = A + (size_t)(m0 + row) * lda + k0 + seg * 8;
    float4 a0 = *(const float4*)pa, a1 = *(const float4*)(pa + 4);
    const float* pb = B + (size_t)(n0 + row) * ldb + k0 + seg * 8;
    float4 b0 = *(const float4*)pb, b1 = *(const float4*)(pb + 4);
    if (k0) __syncthreads();
    *(bf16x8*)&As[row][seg * 8] = pack8(a0, a1);
    *(bf16x8*)&Bs[row][seg * 8] = pack8(b0, b1);
    __syncthreads();
    bf16x8 af = *(const bf16x8*)&As[wid * 16 + lr][lhi * 8];
#pragma unroll
    for (int t = 0; t < 4; ++t) {
      bf16x8 bf = *(const bf16x8*)&Bs[t * 16 + lr][lhi * 8];
      acc[t] = __builtin_amdgcn_mfma_f32_16x16x32_bf16(af, bf, acc[t], 0, 0, 0);
    }
  }
#pragma unroll
  for (int t = 0; t < 4; ++t) {
    const int n = n0 + t * 16 + lr;
#pragma unroll
    for (int r = 0; r < 4; ++r) {
      const int m = m0 + wid * 16 + lhi * 4 + r;
      float v = acc[t][r];
      if (EPI == EPI_NONE) {
        C[(size_t)m * ldc + n] = v;
      } else if (EPI == EPI_BIAS_GELU) {
        v += bias[n];
        C[(size_t)m * ldc + n] = gelu_f(v);
      } else if (EPI == EPI_SOFTPLUS) {
        v += bias[n];
        C[(size_t)m * ldc + n] = softplus_f(v);
      } else if (EPI == EPI_RESID) {
        C[(size_t)m * ldc + n] += v;
      } else if (EPI == EPI_INPROJ) {
        if (n < D_INNER) C[(size_t)m * D_INNER + n] = v;
        else             out2[(size_t)m * D_INNER + (n - D_INNER)] = silu_f(v);
      }
    }
  }
}

// ---------------- layernorm (validated) ----------------
__global__ __launch_bounds__(256) void ln_rows(const float* __restrict__ in,
                                               const float* __restrict__ w,
                                               const float* __restrict__ b,
                                               float* __restrict__ out) {
  __shared__ double red[4];
  const int row = blockIdx.x, t = threadIdx.x;
  const float* r = in + (size_t)row * D_MODEL;
  double x0 = (double)r[t], x1 = (double)r[t + 256];
  double s = x0 + x1;
#pragma unroll
  for (int o = 32; o >= 1; o >>= 1) s += __shfl_down(s, o);
  int wid = t >> 6, lane = t & 63;
  if (lane == 0) red[wid] = s;
  __syncthreads();
  double mu = (red[0] + red[1] + red[2] + red[3]) * (1.0 / 512.0);
  __syncthreads();
  double d0 = x0 - mu, d1 = x1 - mu;
  double v = d0 * d0 + d1 * d1;
#pragma unroll
  for (int o = 32; o >= 1; o >>= 1) v += __shfl_down(v, o);
  if (lane == 0) red[wid] = v;
  __syncthreads();
  double var = (red[0] + red[1] + red[2] + red[3]) * (1.0 / 512.0);
  double rs = rsqrt(var + 1e-5);
  out[(size_t)row * D_MODEL + t]       = (float)(d0 * rs * (double)w[t] + (double)b[t]);
  out[(size_t)row * D_MODEL + t + 256] = (float)(d1 * rs * (double)w[t + 256] + (double)b[t + 256]);
}

// ---------------- causal depthwise conv + bias + silu ----------------
__global__ __launch_bounds__(256) void conv_silu2(const float* __restrict__ xcr,
                                                  const float* __restrict__ cw,
                                                  const float* __restrict__ cb,
                                                  float* __restrict__ out) {
  const int l = blockIdx.x;
  for (int q = 0; q < 4; ++q) {
    const int d = threadIdx.x + q * 256;
    float acc = cb[d];
#pragma unroll
    for (int k = 0; k < 4; ++k) {
      const int ll = l + k - 3;
      const float xv = (ll >= 0) ? xcr[(size_t)ll * D_INNER + d] : 0.0f;
      acc = fmaf(xv, cw[d * 4 + k], acc);
    }
    out[(size_t)l * D_INNER + d] = silu_f(acc);
  }
}

// ---------------- selective scan (3-pass chunked, lane-per-d layout) ----------------
// Each lane owns one d; the 16 states live in registers (fully unrolled n-loop).
// dt/xc/y accesses are coalesced; B/C rows are wave-uniform broadcast float4 loads.

// pass A: per chunk: S = local end state (s_in=0), P = exp2(a2 * sum(dt))
__global__ __launch_bounds__(256) void scanA(const float* __restrict__ dt,
                                             const float* __restrict__ dbc,
                                             const float* __restrict__ xc,
                                             const float* __restrict__ Alog,
                                             float* __restrict__ P, float* __restrict__ S) {
  const int c = blockIdx.y;
  const int d = blockIdx.x * 256 + threadIdx.x;
  float a2[16], s[16];
#pragma unroll
  for (int q = 0; q < 4; ++q) {
    float4 al = *(const float4*)(Alog + (size_t)d * 16 + q * 4);
    a2[4*q+0] = -expf(al.x) * LOG2E; a2[4*q+1] = -expf(al.y) * LOG2E;
    a2[4*q+2] = -expf(al.z) * LOG2E; a2[4*q+3] = -expf(al.w) * LOG2E;
  }
#pragma unroll
  for (int n = 0; n < 16; ++n) s[n] = 0.0f;
  float sdt = 0.0f;
  const int l0 = c * CHUNK;
#pragma unroll 2
  for (int t = 0; t < CHUNK; ++t) {
    const int l = l0 + t;
    const float dtv = dt[(size_t)l * D_INNER + d];
    const float xv  = xc[(size_t)l * D_INNER + d];
    const float dx = dtv * xv;
    sdt += dtv;
    float bv[16];
    const float4* B4 = (const float4*)(dbc + (size_t)l * 64 + DT_RANK);
    *(float4*)&bv[0]  = B4[0]; *(float4*)&bv[4]  = B4[1];
    *(float4*)&bv[8]  = B4[2]; *(float4*)&bv[12] = B4[3];
#pragma unroll
    for (int n = 0; n < 16; ++n)
      s[n] = fmaf(exp2f(dtv * a2[n]), s[n], bv[n] * dx);
  }
  float4* Sp = (float4*)(S + (size_t)c * NREC + (size_t)d * 16);
  float4* Pp = (float4*)(P + (size_t)c * NREC + (size_t)d * 16);
#pragma unroll
  for (int q = 0; q < 4; ++q) {
    Sp[q] = make_float4(s[4*q], s[4*q+1], s[4*q+2], s[4*q+3]);
    Pp[q] = make_float4(exp2f(a2[4*q]*sdt), exp2f(a2[4*q+1]*sdt),
                        exp2f(a2[4*q+2]*sdt), exp2f(a2[4*q+3]*sdt));
  }
}

// pass B: sequential over chunks -> exclusive carry
__global__ __launch_bounds__(256) void scanB(const float* __restrict__ P,
                                             const float* __restrict__ S,
                                             float* __restrict__ carry) {
  int idx = blockIdx.x * 256 + threadIdx.x;  // [0, NREC)
  float cr = 0.0f;
  for (int c = 0; c < NCHUNK; ++c) {
    size_t k = (size_t)c * NREC + idx;
    carry[k] = cr;
    cr = fmaf(P[k], cr, S[k]);
  }
}

// pass C: replay with carry; y = (sum_n s*C + xc*D) * silu_z (all in registers)
__global__ __launch_bounds__(256) void scanC(const float* __restrict__ dt,
                                             const float* __restrict__ dbc,
                                             const float* __restrict__ xc,
                                             const float* __restrict__ Alog,
                                             const float* __restrict__ carry,
                                             const float* __restrict__ Dskip,
                                             const float* __restrict__ zs,
                                             float* __restrict__ y) {
  const int c = blockIdx.y;
  const int d = blockIdx.x * 256 + threadIdx.x;
  float a2[16], s[16];
#pragma unroll
  for (int q = 0; q < 4; ++q) {
    float4 al = *(const float4*)(Alog + (size_t)d * 16 + q * 4);
    a2[4*q+0] = -expf(al.x) * LOG2E; a2[4*q+1] = -expf(al.y) * LOG2E;
    a2[4*q+2] = -expf(al.z) * LOG2E; a2[4*q+3] = -expf(al.w) * LOG2E;
    float4 cr = *(const float4*)(carry + (size_t)c * NREC + (size_t)d * 16 + q * 4);
    s[4*q+0] = cr.x; s[4*q+1] = cr.y; s[4*q+2] = cr.z; s[4*q+3] = cr.w;
  }
  const float dsk = Dskip[d];
  const int l0 = c * CHUNK;
#pragma unroll 2
  for (int t = 0; t < CHUNK; ++t) {
    const int l = l0 + t;
    const float dtv = dt[(size_t)l * D_INNER + d];
    const float xv  = xc[(size_t)l * D_INNER + d];
    const float dx = dtv * xv;
    float bv[16], cv[16];
    const float4* B4 = (const float4*)(dbc + (size_t)l * 64 + DT_RANK);
    *(float4*)&bv[0]  = B4[0]; *(float4*)&bv[4]  = B4[1];
    *(float4*)&bv[8]  = B4[2]; *(float4*)&bv[12] = B4[3];
    *(float4*)&cv[0]  = B4[4]; *(float4*)&cv[4]  = B4[5];
    *(float4*)&cv[8]  = B4[6]; *(float4*)&cv[12] = B4[7];
    float acc = 0.0f;
#pragma unroll
    for (int n = 0; n < 16; ++n) {
      s[n] = fmaf(exp2f(dtv * a2[n]), s[n], bv[n] * dx);
      acc = fmaf(s[n], cv[n], acc);
    }
    float yv = fmaf(xv, dsk, acc);
    y[(size_t)l * D_INNER + d] = yv * zs[(size_t)l * D_INNER + d];
  }
}

// ---------------- final head (validated) ----------------
__global__ __launch_bounds__(512) void colsum(const float* __restrict__ h, double* __restrict__ part) {
  int d = threadIdx.x;
  int r0 = blockIdx.x * 128;
  double s = 0.0;
  for (int r = 0; r < 128; ++r) s += (double)h[(size_t)(r0 + r) * D_MODEL + d];
  part[blockIdx.x * D_MODEL + d] = s;
}

__global__ __launch_bounds__(512) void head_k(const double* __restrict__ part,
                                              const float* __restrict__ cls_w,
                                              const float* __restrict__ cls_b,
                                              float* __restrict__ out) {
  __shared__ double l0[512], l1[512];
  int d = threadIdx.x;
  double s = 0.0;
  for (int b = 0; b < 32; ++b) s += part[b * D_MODEL + d];
  double hv = s * (1.0 / 4096.0);
  out[d] = (float)hv;
  l0[d] = hv * (double)cls_w[d];
  l1[d] = hv * (double)cls_w[D_MODEL + d];
  __syncthreads();
  for (int o = 256; o > 0; o >>= 1) {
    if (d < o) { l0[d] += l0[d + o]; l1[d] += l1[d + o]; }
    __syncthreads();
  }
  if (d == 0) { out[512] = (float)(l0[0] + (double)cls_b[0]); out[513] = (float)(l1[0] + (double)cls_b[1]); }
}

// ---------------- launch ----------------
extern "C" void kernel_launch(void* const* d_in, const int* in_sizes, int n_in,
                              void* d_out, int out_size, void* d_ws, size_t ws_size,
                              hipStream_t stream) {
  const float* x         = (const float*)d_in[0];
  const float* fc1_w     = (const float*)d_in[1];
  const float* fc1_b     = (const float*)d_in[2];
  const float* ln_w      = (const float*)d_in[3];
  const float* ln_b      = (const float*)d_in[4];
  const float* in_proj_w = (const float*)d_in[5];
  const float* conv_w    = (const float*)d_in[6];
  const float* conv_b    = (const float*)d_in[7];
  const float* x_proj_w  = (const float*)d_in[8];
  const float* dt_proj_w = (const float*)d_in[9];
  const float* dt_proj_b = (const float*)d_in[10];
  const float* A_log     = (const float*)d_in[11];
  const float* D_skip    = (const float*)d_in[12];
  const float* norm_w    = (const float*)d_in[13];
  const float* norm_b    = (const float*)d_in[14];
  const float* cls_w     = (const float*)d_in[15];
  const float* cls_b     = (const float*)d_in[16];
  float* out = (float*)d_out;
  float* ws  = (float*)d_ws;

  float* h_buf   = ws + OFF_H;
  float* hn_buf  = ws + OFF_HN;
  float* carry_b = ws + OFF_HN;                  // overlays hn (dead after in_proj)
  float* y_buf   = ws + OFF_XCRAW;               // xcraw -> P/S -> y
  float* P_buf   = ws + OFF_XCRAW;               // P (2M), dead after scanB
  float* S_buf   = ws + OFF_XCRAW + 2097152;     // S (2M), dead after scanB
  float* z_buf   = ws + OFF_Z;
  float* xc_buf  = ws + OFF_XC;
  float* dt_buf  = ws + OFF_DT;
  float* dbc_buf = ws + OFF_DBC;
  float* wout    = ws + OFF_WOUT;
  double* part   = (double*)(ws + OFF_PART);

  gen_wout<<<4096, 256, 0, stream>>>(wout);

  // h = gelu(x @ fc1_w^T + fc1_b)    [4096,512]
  gemm_mfma<EPI_BIAS_GELU><<<dim3(8, 64), 256, 0, stream>>>(
      x, IN_DIM, fc1_w, IN_DIM, h_buf, D_MODEL, IN_DIM, fc1_b, nullptr);

  for (int i = 0; i < 2; ++i) {
    const float* Wi = in_proj_w + (size_t)i * 2 * D_INNER * D_MODEL;
    // hn = LN(h)
    ln_rows<<<4096, 256, 0, stream>>>(h_buf, ln_w + i * D_MODEL, ln_b + i * D_MODEL, hn_buf);
    // xz = hn @ Wi^T -> xcraw (n<1024), silu(z) (n>=1024)
    gemm_mfma<EPI_INPROJ><<<dim3(32, 64), 256, 0, stream>>>(
        hn_buf, D_MODEL, Wi, D_MODEL, y_buf /*=xcraw*/, D_INNER, D_MODEL, nullptr, z_buf);
    // xc = silu(conv(xcraw) + conv_b)
    conv_silu2<<<4096, 256, 0, stream>>>(y_buf, conv_w + (size_t)i * D_INNER * 4,
                                         conv_b + i * D_INNER, xc_buf);
    // dbc = xc @ x_proj_w^T   [4096,64]
    gemm_mfma<EPI_NONE><<<dim3(1, 64), 256, 0, stream>>>(
        xc_buf, D_INNER, x_proj_w + (size_t)i * 64 * D_INNER, D_INNER,
        dbc_buf, 64, D_INNER, nullptr, nullptr);
    // dt = softplus(dbc[:, :32] @ dt_proj_w^T + dt_proj_b)   [4096,1024]
    gemm_mfma<EPI_SOFTPLUS><<<dim3(16, 64), 256, 0, stream>>>(
        dbc_buf, 64, dt_proj_w + (size_t)i * D_INNER * DT_RANK, DT_RANK,
        dt_buf, D_INNER, DT_RANK, dt_proj_b + i * D_INNER, nullptr);
    // selective scan -> y (fused y-assembly)
    const float* Alog_i = A_log + (size_t)i * D_INNER * D_STATE;
    scanA<<<dim3(4, NCHUNK), 256, 0, stream>>>(dt_buf, dbc_buf, xc_buf, Alog_i, P_buf, S_buf);
    scanB<<<64, 256, 0, stream>>>(P_buf, S_buf, carry_b);
    scanC<<<dim3(4, NCHUNK), 256, 0, stream>>>(dt_buf, dbc_buf, xc_buf, Alog_i, carry_b,
                                               D_skip + i * D_INNER, z_buf, y_buf);
    // h += y @ wout^T   (fused residual)
    gemm_mfma<EPI_RESID><<<dim3(8, 64), 256, 0, stream>>>(
        y_buf, D_INNER, wout + (size_t)i * D_MODEL * D_INNER, D_INNER,
        h_buf, D_MODEL, D_INNER, nullptr, nullptr);
  }

  ln_rows<<<4096, 256, 0, stream>>>(h_buf, norm_w, norm_b, out + 514);
  colsum<<<32, 512, 0, stream>>>(out + 514, part);
  head_k<<<1, 512, 0, stream>>>(part, cls_w, cls_b, out);
}

// Round 8
// 400.087 us; speedup vs baseline: 3.5513x; 1.1898x over previous
//
#include <hip/hip_runtime.h>
#include <cstdint>
#include <cstddef>

// ---------------- constants ----------------
#define SEQ     4096
#define IN_DIM  1024
#define D_MODEL 512
#define D_INNER 1024
#define D_STATE 16
#define DT_RANK 32

#define CHUNK   32
#define NCHUNK  128    // SEQ / CHUNK
#define NREC    16384  // D_INNER * D_STATE

#define LOG2E 1.44269504088896f

// ---------------- workspace layout (float offsets) ----------------
// 0        h f32 (2M)
// 2M       xcraw f32 (4M) -> P (2M@2M) + S (2M@4M) -> y_bf16 (2M fl-eq @2M)
// 6M       z f32 (4M)
// 10M      xc f32 (4M)
// 14M      dt f32 (4M); transient overlays BEFORE dt is written:
//            x_bf16 (2M fl-eq @14M, dead after fc1)
//            xc_bf16 (2M fl-eq @14M, conv->dbc GEMM, dead before dt GEMM writes)
// 18M      carry f32 (2M); transient fc1w_bf16 (0.25M fl-eq, dead after fc1)
// 20M      hn_bf16 (0.5M fl-eq)
// 20.5M    Wi_bf16 (0.5M fl-eq)
// 21M      dbc f32 (256K)
// +        dbc_bf16 (128K fl-eq), xpw_bf16 (32K), dpw_bf16 (16K), wout_bf16 (512K), part
static const size_t OFF_H     = 0;
static const size_t OFF_PS    = 2097152;                 // P @2M, S @4M; y_bf / xcraw here
static const size_t OFF_Z     = 6291456;
static const size_t OFF_XC    = 10485760;
static const size_t OFF_DT    = 14680064;
static const size_t OFF_CARRY = 18874368;
static const size_t OFF_HNB   = 20971520;
static const size_t OFF_WIB   = 21495808;
static const size_t OFF_DBCF  = 22020096;
static const size_t OFF_DBCB  = 22282240;
static const size_t OFF_XPWB  = 22413312;
static const size_t OFF_DPWB  = 22446080;
static const size_t OFF_WOUTB = 22462464;
static const size_t OFF_PART  = 22986752;
// end ~ 23.02M floats = 92.1 MB (under proven-safe 93.5 MB)

typedef __attribute__((ext_vector_type(8))) short bf16x8;
typedef __attribute__((ext_vector_type(4))) float f32x4;

// ---------------- jax threefry / normal reproduction (VALIDATED round 4) ----------------
__device__ __forceinline__ uint32_t rotl32(uint32_t v, int r) { return (v << r) | (v >> (32 - r)); }

__device__ __forceinline__ void threefry2x32(uint32_t k0, uint32_t k1, uint32_t x0, uint32_t x1,
                                             uint32_t& o0, uint32_t& o1) {
  uint32_t ks0 = k0, ks1 = k1, ks2 = k0 ^ k1 ^ 0x1BD11BDAu;
  x0 += ks0; x1 += ks1;
  const int rotA[4] = {13, 15, 26, 6};
  const int rotB[4] = {17, 29, 16, 24};
  uint32_t ks[3] = {ks0, ks1, ks2};
#pragma unroll
  for (int r = 0; r < 5; ++r) {
    const int* rr = (r & 1) ? rotB : rotA;
#pragma unroll
    for (int j = 0; j < 4; ++j) { x0 += x1; x1 = rotl32(x1, rr[j]); x1 ^= x0; }
    x0 += ks[(r + 1) % 3];
    x1 += ks[(r + 2) % 3] + (uint32_t)(r + 1);
  }
  o0 = x0; o1 = x1;
}

__device__ __forceinline__ float erfinv32(float x) {
  float w = -log1pf(-x * x);
  float p;
  if (w < 5.0f) {
    w -= 2.5f;
    p = 2.81022636e-08f;
    p = fmaf(p, w, 3.43273939e-07f);
    p = fmaf(p, w, -3.5233877e-06f);
    p = fmaf(p, w, -4.39150654e-06f);
    p = fmaf(p, w, 0.00021858087f);
    p = fmaf(p, w, -0.00125372503f);
    p = fmaf(p, w, -0.00417768164f);
    p = fmaf(p, w, 0.246640727f);
    p = fmaf(p, w, 1.50140941f);
  } else {
    w = sqrtf(w) - 3.0f;
    p = -0.000200214257f;
    p = fmaf(p, w, 0.000100950558f);
    p = fmaf(p, w, 0.00134934322f);
    p = fmaf(p, w, -0.00367342844f);
    p = fmaf(p, w, 0.00573950773f);
    p = fmaf(p, w, -0.0076224613f);
    p = fmaf(p, w, 0.00943887047f);
    p = fmaf(p, w, 1.00167406f);
    p = fmaf(p, w, 2.83297682f);
  }
  return p * x;
}

__device__ __forceinline__ float bits_to_normal(uint32_t b) {
  float f = __uint_as_float((b >> 9) | 0x3f800000u) - 1.0f;
  const float lo = -0.99999994f;
  float u = f * (1.0f - lo) + lo;
  u = fmaxf(lo, u);
  return 1.41421356f * erfinv32(u);
}

// ---------------- bf16 conversion (RNE) ----------------
__device__ __forceinline__ ushort f2bf(float x) {
  uint32_t u = __float_as_uint(x);
  u = (u + 0x7FFFu + ((u >> 16) & 1u)) >> 16;
  return (ushort)u;
}
__device__ __forceinline__ bf16x8 pack8(float4 a, float4 b) {
  bf16x8 v;
  v[0] = f2bf(a.x); v[1] = f2bf(a.y); v[2] = f2bf(a.z); v[3] = f2bf(a.w);
  v[4] = f2bf(b.x); v[5] = f2bf(b.y); v[6] = f2bf(b.z); v[7] = f2bf(b.w);
  return v;
}

// PARTITIONABLE threefry bits -> bf16 weights directly
__global__ __launch_bounds__(256) void gen_wout(ushort* __restrict__ w) {
  int gid = blockIdx.x * 256 + threadIdx.x;        // [0, 2*524288)
  int layer = gid >> 19;
  int j = gid & 0x7FFFF;
  uint32_t k0, k1;
  threefry2x32(0u, 7u, 0u, (uint32_t)layer, k0, k1);   // fold_in(key(7), layer)
  uint32_t o0, o1;
  threefry2x32(k0, k1, 0u, (uint32_t)j, o0, o1);
  w[(size_t)layer * 524288 + j] = f2bf(bits_to_normal(o0 ^ o1) * 0.02f);
}

// ---------------- f32 -> bf16 bulk conversion ----------------
__global__ __launch_bounds__(256) void f32_to_bf16(const float* __restrict__ in,
                                                   ushort* __restrict__ out, int n8) {
  int i = blockIdx.x * 256 + threadIdx.x;
  if (i >= n8) return;
  const float4* p = (const float4*)(in + (size_t)i * 8);
  *(bf16x8*)(out + (size_t)i * 8) = pack8(p[0], p[1]);
}

// ---------------- activations ----------------
__device__ __forceinline__ float silu_f(float v) { return v / (1.0f + exp2f(-LOG2E * v)); }
__device__ __forceinline__ float gelu_f(float v) {
  float v3 = v * v * v;
  return 0.5f * v * (1.0f + tanhf(0.7978845608028654f * (v + 0.044715f * v3)));
}
__device__ __forceinline__ float softplus_f(float v) {
  return fmaxf(v, 0.0f) + log1pf(exp2f(-LOG2E * fabsf(v)));
}

// ---------------- bf16 MFMA GEMM: C[M,N] = A[M,K] * B[N,K]^T, bf16 in, f32 out ----------------
// MT=64, NT=128|64, BK=32, 256 threads (4 waves), LDS double-buffer + register prefetch.
// C/D map (m89): col = lane&15, row = (lane>>4)*4 + reg. Wave w owns rows [w*16, w*16+16).
enum { EPI_NONE = 0, EPI_BIAS_GELU = 1, EPI_INPROJ = 2, EPI_SOFTPLUS = 3, EPI_RESID = 4, EPI_DBC = 5 };

template <int EPI, int NT>
__global__ __launch_bounds__(256) void gemm_bf(
    const ushort* __restrict__ A, int lda,
    const ushort* __restrict__ B, int ldb,
    float* __restrict__ C, int ldc, int K,
    const float* __restrict__ bias, float* __restrict__ out2,
    ushort* __restrict__ outb) {
  constexpr int NB = NT / 64;   // B-chunks per thread (1 or 2)
  __shared__ ushort As[2][64][40];
  __shared__ ushort Bs[2][NT][40];
  const int m0 = blockIdx.y * 64, n0 = blockIdx.x * NT;
  const int tid = threadIdx.x;
  const int arow = tid >> 2, ach = (tid & 3) * 8;
  const int lane = tid & 63, wid = tid >> 6;
  const int lr = lane & 15, lhi = lane >> 4;
  const ushort* Ap  = A + (size_t)(m0 + arow) * lda + ach;
  const ushort* Bp0 = B + (size_t)(n0 + arow) * ldb + ach;
  const ushort* Bp1 = (NB > 1) ? (B + (size_t)(n0 + 64 + arow) * ldb + ach) : Bp0;

  f32x4 acc[NT / 16] = {};
  uint4 ra, rb0, rb1;

  ra  = *(const uint4*)Ap;
  rb0 = *(const uint4*)Bp0;
  if (NB > 1) rb1 = *(const uint4*)Bp1;
  *(uint4*)&As[0][arow][ach] = ra;
  *(uint4*)&Bs[0][arow][ach] = rb0;
  if (NB > 1) *(uint4*)&Bs[0][64 + arow][ach] = rb1;
  __syncthreads();

  const int nk = K >> 5;
  int cur = 0;
  for (int ki = 0; ki < nk; ++ki) {
    const bool more = (ki + 1 < nk);
    if (more) {
      const int k = (ki + 1) << 5;
      ra  = *(const uint4*)(Ap + k);
      rb0 = *(const uint4*)(Bp0 + k);
      if (NB > 1) rb1 = *(const uint4*)(Bp1 + k);
    }
    bf16x8 af = *(const bf16x8*)&As[cur][wid * 16 + lr][lhi * 8];
#pragma unroll
    for (int t = 0; t < NT / 16; ++t) {
      bf16x8 bv = *(const bf16x8*)&Bs[cur][t * 16 + lr][lhi * 8];
      acc[t] = __builtin_amdgcn_mfma_f32_16x16x32_bf16(af, bv, acc[t], 0, 0, 0);
    }
    if (more) {
      *(uint4*)&As[cur ^ 1][arow][ach] = ra;
      *(uint4*)&Bs[cur ^ 1][arow][ach] = rb0;
      if (NB > 1) *(uint4*)&Bs[cur ^ 1][64 + arow][ach] = rb1;
    }
    __syncthreads();
    cur ^= 1;
  }

#pragma unroll
  for (int t = 0; t < NT / 16; ++t) {
    const int n = n0 + t * 16 + lr;
#pragma unroll
    for (int r = 0; r < 4; ++r) {
      const int m = m0 + wid * 16 + lhi * 4 + r;
      float v = acc[t][r];
      if (EPI == EPI_NONE) {
        C[(size_t)m * ldc + n] = v;
      } else if (EPI == EPI_BIAS_GELU) {
        v += bias[n];
        C[(size_t)m * ldc + n] = gelu_f(v);
      } else if (EPI == EPI_SOFTPLUS) {
        v += bias[n];
        C[(size_t)m * ldc + n] = softplus_f(v);
      } else if (EPI == EPI_RESID) {
        C[(size_t)m * ldc + n] += v;
      } else if (EPI == EPI_INPROJ) {
        if (n < D_INNER) C[(size_t)m * D_INNER + n] = v;
        else             out2[(size_t)m * D_INNER + (n - D_INNER)] = silu_f(v);
      } else if (EPI == EPI_DBC) {
        C[(size_t)m * 64 + n] = v;
        outb[(size_t)m * 64 + n] = f2bf(v);
      }
    }
  }
}

// ---------------- layernorm (validated math, templated output) ----------------
template <int BF>
__global__ __launch_bounds__(256) void ln_rows(const float* __restrict__ in,
                                               const float* __restrict__ w,
                                               const float* __restrict__ b,
                                               float* __restrict__ outf,
                                               ushort* __restrict__ outb) {
  __shared__ double red[4];
  const int row = blockIdx.x, t = threadIdx.x;
  const float* r = in + (size_t)row * D_MODEL;
  double x0 = (double)r[t], x1 = (double)r[t + 256];
  double s = x0 + x1;
#pragma unroll
  for (int o = 32; o >= 1; o >>= 1) s += __shfl_down(s, o);
  int wid = t >> 6, lane = t & 63;
  if (lane == 0) red[wid] = s;
  __syncthreads();
  double mu = (red[0] + red[1] + red[2] + red[3]) * (1.0 / 512.0);
  __syncthreads();
  double d0 = x0 - mu, d1 = x1 - mu;
  double v = d0 * d0 + d1 * d1;
#pragma unroll
  for (int o = 32; o >= 1; o >>= 1) v += __shfl_down(v, o);
  if (lane == 0) red[wid] = v;
  __syncthreads();
  double var = (red[0] + red[1] + red[2] + red[3]) * (1.0 / 512.0);
  double rs = rsqrt(var + 1e-5);
  float o0 = (float)(d0 * rs * (double)w[t] + (double)b[t]);
  float o1 = (float)(d1 * rs * (double)w[t + 256] + (double)b[t + 256]);
  if (BF) {
    outb[(size_t)row * D_MODEL + t]       = f2bf(o0);
    outb[(size_t)row * D_MODEL + t + 256] = f2bf(o1);
  } else {
    outf[(size_t)row * D_MODEL + t]       = o0;
    outf[(size_t)row * D_MODEL + t + 256] = o1;
  }
}

// ---------------- causal depthwise conv + bias + silu -> f32 + bf16 ----------------
__global__ __launch_bounds__(256) void conv_silu2(const float* __restrict__ xcr,
                                                  const float* __restrict__ cw,
                                                  const float* __restrict__ cb,
                                                  float* __restrict__ outf,
                                                  ushort* __restrict__ outb) {
  const int l = blockIdx.x;
  for (int q = 0; q < 4; ++q) {
    const int d = threadIdx.x + q * 256;
    float acc = cb[d];
#pragma unroll
    for (int k = 0; k < 4; ++k) {
      const int ll = l + k - 3;
      const float xv = (ll >= 0) ? xcr[(size_t)ll * D_INNER + d] : 0.0f;
      acc = fmaf(xv, cw[d * 4 + k], acc);
    }
    float o = silu_f(acc);
    outf[(size_t)l * D_INNER + d] = o;
    outb[(size_t)l * D_INNER + d] = f2bf(o);
  }
}

// ---------------- selective scan (lane-per-d layout; validated round 7) ----------------
__global__ __launch_bounds__(256) void scanA(const float* __restrict__ dt,
                                             const float* __restrict__ dbc,
                                             const float* __restrict__ xc,
                                             const float* __restrict__ Alog,
                                             float* __restrict__ P, float* __restrict__ S) {
  const int c = blockIdx.y;
  const int d = blockIdx.x * 256 + threadIdx.x;
  float a2[16], s[16];
#pragma unroll
  for (int q = 0; q < 4; ++q) {
    float4 al = *(const float4*)(Alog + (size_t)d * 16 + q * 4);
    a2[4*q+0] = -expf(al.x) * LOG2E; a2[4*q+1] = -expf(al.y) * LOG2E;
    a2[4*q+2] = -expf(al.z) * LOG2E; a2[4*q+3] = -expf(al.w) * LOG2E;
  }
#pragma unroll
  for (int n = 0; n < 16; ++n) s[n] = 0.0f;
  float sdt = 0.0f;
  const int l0 = c * CHUNK;
#pragma unroll 2
  for (int t = 0; t < CHUNK; ++t) {
    const int l = l0 + t;
    const float dtv = dt[(size_t)l * D_INNER + d];
    const float xv  = xc[(size_t)l * D_INNER + d];
    const float dx = dtv * xv;
    sdt += dtv;
    float bv[16];
    const float4* B4 = (const float4*)(dbc + (size_t)l * 64 + DT_RANK);
    *(float4*)&bv[0]  = B4[0]; *(float4*)&bv[4]  = B4[1];
    *(float4*)&bv[8]  = B4[2]; *(float4*)&bv[12] = B4[3];
#pragma unroll
    for (int n = 0; n < 16; ++n)
      s[n] = fmaf(exp2f(dtv * a2[n]), s[n], bv[n] * dx);
  }
  float4* Sp = (float4*)(S + (size_t)c * NREC + (size_t)d * 16);
  float4* Pp = (float4*)(P + (size_t)c * NREC + (size_t)d * 16);
#pragma unroll
  for (int q = 0; q < 4; ++q) {
    Sp[q] = make_float4(s[4*q], s[4*q+1], s[4*q+2], s[4*q+3]);
    Pp[q] = make_float4(exp2f(a2[4*q]*sdt), exp2f(a2[4*q+1]*sdt),
                        exp2f(a2[4*q+2]*sdt), exp2f(a2[4*q+3]*sdt));
  }
}

__global__ __launch_bounds__(256) void scanB(const float* __restrict__ P,
                                             const float* __restrict__ S,
                                             float* __restrict__ carry) {
  int idx = blockIdx.x * 256 + threadIdx.x;
  float cr = 0.0f;
  for (int c = 0; c < NCHUNK; ++c) {
    size_t k = (size_t)c * NREC + idx;
    carry[k] = cr;
    cr = fmaf(P[k], cr, S[k]);
  }
}

// pass C: y (bf16) = (sum_n s*C + xc*D) * silu_z
__global__ __launch_bounds__(256) void scanC(const float* __restrict__ dt,
                                             const float* __restrict__ dbc,
                                             const float* __restrict__ xc,
                                             const float* __restrict__ Alog,
                                             const float* __restrict__ carry,
                                             const float* __restrict__ Dskip,
                                             const float* __restrict__ zs,
                                             ushort* __restrict__ yb) {
  const int c = blockIdx.y;
  const int d = blockIdx.x * 256 + threadIdx.x;
  float a2[16], s[16];
#pragma unroll
  for (int q = 0; q < 4; ++q) {
    float4 al = *(const float4*)(Alog + (size_t)d * 16 + q * 4);
    a2[4*q+0] = -expf(al.x) * LOG2E; a2[4*q+1] = -expf(al.y) * LOG2E;
    a2[4*q+2] = -expf(al.z) * LOG2E; a2[4*q+3] = -expf(al.w) * LOG2E;
    float4 cr = *(const float4*)(carry + (size_t)c * NREC + (size_t)d * 16 + q * 4);
    s[4*q+0] = cr.x; s[4*q+1] = cr.y; s[4*q+2] = cr.z; s[4*q+3] = cr.w;
  }
  const float dsk = Dskip[d];
  const int l0 = c * CHUNK;
#pragma unroll 2
  for (int t = 0; t < CHUNK; ++t) {
    const int l = l0 + t;
    const float dtv = dt[(size_t)l * D_INNER + d];
    const float xv  = xc[(size_t)l * D_INNER + d];
    const float dx = dtv * xv;
    float bv[16], cv[16];
    const float4* B4 = (const float4*)(dbc + (size_t)l * 64 + DT_RANK);
    *(float4*)&bv[0]  = B4[0]; *(float4*)&bv[4]  = B4[1];
    *(float4*)&bv[8]  = B4[2]; *(float4*)&bv[12] = B4[3];
    *(float4*)&cv[0]  = B4[4]; *(float4*)&cv[4]  = B4[5];
    *(float4*)&cv[8]  = B4[6]; *(float4*)&cv[12] = B4[7];
    float acc = 0.0f;
#pragma unroll
    for (int n = 0; n < 16; ++n) {
      s[n] = fmaf(exp2f(dtv * a2[n]), s[n], bv[n] * dx);
      acc = fmaf(s[n], cv[n], acc);
    }
    float yv = fmaf(xv, dsk, acc);
    yb[(size_t)l * D_INNER + d] = f2bf(yv * zs[(size_t)l * D_INNER + d]);
  }
}

// ---------------- final head (validated) ----------------
__global__ __launch_bounds__(512) void colsum(const float* __restrict__ h, double* __restrict__ part) {
  int d = threadIdx.x;
  int r0 = blockIdx.x * 128;
  double s = 0.0;
  for (int r = 0; r < 128; ++r) s += (double)h[(size_t)(r0 + r) * D_MODEL + d];
  part[blockIdx.x * D_MODEL + d] = s;
}

__global__ __launch_bounds__(512) void head_k(const double* __restrict__ part,
                                              const float* __restrict__ cls_w,
                                              const float* __restrict__ cls_b,
                                              float* __restrict__ out) {
  __shared__ double l0[512], l1[512];
  int d = threadIdx.x;
  double s = 0.0;
  for (int b = 0; b < 32; ++b) s += part[b * D_MODEL + d];
  double hv = s * (1.0 / 4096.0);
  out[d] = (float)hv;
  l0[d] = hv * (double)cls_w[d];
  l1[d] = hv * (double)cls_w[D_MODEL + d];
  __syncthreads();
  for (int o = 256; o > 0; o >>= 1) {
    if (d < o) { l0[d] += l0[d + o]; l1[d] += l1[d + o]; }
    __syncthreads();
  }
  if (d == 0) { out[512] = (float)(l0[0] + (double)cls_b[0]); out[513] = (float)(l1[0] + (double)cls_b[1]); }
}

// ---------------- launch ----------------
extern "C" void kernel_launch(void* const* d_in, const int* in_sizes, int n_in,
                              void* d_out, int out_size, void* d_ws, size_t ws_size,
                              hipStream_t stream) {
  const float* x         = (const float*)d_in[0];
  const float* fc1_w     = (const float*)d_in[1];
  const float* fc1_b     = (const float*)d_in[2];
  const float* ln_w      = (const float*)d_in[3];
  const float* ln_b      = (const float*)d_in[4];
  const float* in_proj_w = (const float*)d_in[5];
  const float* conv_w    = (const float*)d_in[6];
  const float* conv_b    = (const float*)d_in[7];
  const float* x_proj_w  = (const float*)d_in[8];
  const float* dt_proj_w = (const float*)d_in[9];
  const float* dt_proj_b = (const float*)d_in[10];
  const float* A_log     = (const float*)d_in[11];
  const float* D_skip    = (const float*)d_in[12];
  const float* norm_w    = (const float*)d_in[13];
  const float* norm_b    = (const float*)d_in[14];
  const float* cls_w     = (const float*)d_in[15];
  const float* cls_b     = (const float*)d_in[16];
  float* out = (float*)d_out;
  float* ws  = (float*)d_ws;

  float*  h_buf   = ws + OFF_H;
  float*  xcraw   = ws + OFF_PS;                  // xcraw f32 (4M)
  float*  P_buf   = ws + OFF_PS;                  // P (2M), after conv
  float*  S_buf   = ws + OFF_PS + 2097152;        // S (2M)
  ushort* y_bf    = (ushort*)(ws + OFF_PS);       // y bf16 (2M fl-eq), after scanB
  float*  z_buf   = ws + OFF_Z;
  float*  xc_buf  = ws + OFF_XC;
  float*  dt_buf  = ws + OFF_DT;
  ushort* x_bf    = (ushort*)(ws + OFF_DT);       // transient (pre-loop)
  ushort* xc_bf   = (ushort*)(ws + OFF_DT);       // transient (conv -> dbc GEMM)
  float*  carry_b = ws + OFF_CARRY;
  ushort* fc1w_bf = (ushort*)(ws + OFF_CARRY);    // transient (pre-loop)
  ushort* hn_bf   = (ushort*)(ws + OFF_HNB);
  ushort* Wi_bf   = (ushort*)(ws + OFF_WIB);
  float*  dbc_f   = ws + OFF_DBCF;
  ushort* dbc_bf  = (ushort*)(ws + OFF_DBCB);
  ushort* xpw_bf  = (ushort*)(ws + OFF_XPWB);
  ushort* dpw_bf  = (ushort*)(ws + OFF_DPWB);
  ushort* wout_bf = (ushort*)(ws + OFF_WOUTB);
  double* part    = (double*)(ws + OFF_PART);

  gen_wout<<<4096, 256, 0, stream>>>(wout_bf);

  // convert fc1 inputs to bf16
  f32_to_bf16<<<2048, 256, 0, stream>>>(x, x_bf, 524288);        // 4096*1024/8
  f32_to_bf16<<<256, 256, 0, stream>>>(fc1_w, fc1w_bf, 65536);   // 512*1024/8

  // h = gelu(x @ fc1_w^T + fc1_b)
  gemm_bf<EPI_BIAS_GELU, 128><<<dim3(4, 64), 256, 0, stream>>>(
      x_bf, IN_DIM, fc1w_bf, IN_DIM, h_buf, D_MODEL, IN_DIM, fc1_b, nullptr, nullptr);

  for (int i = 0; i < 2; ++i) {
    // hn = LN(h) -> bf16
    ln_rows<1><<<4096, 256, 0, stream>>>(h_buf, ln_w + i * D_MODEL, ln_b + i * D_MODEL,
                                         nullptr, hn_bf);
    // Wi -> bf16
    f32_to_bf16<<<512, 256, 0, stream>>>(in_proj_w + (size_t)i * 2 * D_INNER * D_MODEL,
                                         Wi_bf, 131072);
    // xz = hn @ Wi^T -> xcraw f32 (n<1024), silu(z) f32 (n>=1024)
    gemm_bf<EPI_INPROJ, 128><<<dim3(16, 64), 256, 0, stream>>>(
        hn_bf, D_MODEL, Wi_bf, D_MODEL, xcraw, D_INNER, D_MODEL, nullptr, z_buf, nullptr);
    // xc = silu(conv(xcraw)+cb) -> f32 + bf16
    conv_silu2<<<4096, 256, 0, stream>>>(xcraw, conv_w + (size_t)i * D_INNER * 4,
                                         conv_b + i * D_INNER, xc_buf, xc_bf);
    // weight conversions
    f32_to_bf16<<<32, 256, 0, stream>>>(x_proj_w + (size_t)i * 64 * D_INNER, xpw_bf, 8192);
    f32_to_bf16<<<16, 256, 0, stream>>>(dt_proj_w + (size_t)i * D_INNER * DT_RANK, dpw_bf, 4096);
    // dbc = xc @ x_proj_w^T -> f32 + bf16
    gemm_bf<EPI_DBC, 64><<<dim3(1, 64), 256, 0, stream>>>(
        xc_bf, D_INNER, xpw_bf, D_INNER, dbc_f, 64, D_INNER, nullptr, nullptr, dbc_bf);
    // dt = softplus(dbc[:, :32] @ dt_proj_w^T + dt_proj_b)   (overwrites xc_bf region)
    gemm_bf<EPI_SOFTPLUS, 128><<<dim3(8, 64), 256, 0, stream>>>(
        dbc_bf, 64, dpw_bf, DT_RANK, dt_buf, D_INNER, DT_RANK,
        dt_proj_b + i * D_INNER, nullptr, nullptr);
    // selective scan -> y bf16
    const float* Alog_i = A_log + (size_t)i * D_INNER * D_STATE;
    scanA<<<dim3(4, NCHUNK), 256, 0, stream>>>(dt_buf, dbc_f, xc_buf, Alog_i, P_buf, S_buf);
    scanB<<<64, 256, 0, stream>>>(P_buf, S_buf, carry_b);
    scanC<<<dim3(4, NCHUNK), 256, 0, stream>>>(dt_buf, dbc_f, xc_buf, Alog_i, carry_b,
                                               D_skip + i * D_INNER, z_buf, y_bf);
    // h += y @ wout^T
    gemm_bf<EPI_RESID, 128><<<dim3(4, 64), 256, 0, stream>>>(
        y_bf, D_INNER, wout_bf + (size_t)i * 524288, D_INNER, h_buf, D_MODEL, D_INNER,
        nullptr, nullptr, nullptr);
  }

  ln_rows<0><<<4096, 256, 0, stream>>>(h_buf, norm_w, norm_b, out + 514, nullptr);
  colsum<<<32, 512, 0, stream>>>(out + 514, part);
  head_k<<<1, 512, 0, stream>>>(part, cls_w, cls_b, out);
}

// Round 10
// 384.705 us; speedup vs baseline: 3.6933x; 1.0400x over previous
//
#include <hip/hip_runtime.h>
#include <cstdint>
#include <cstddef>

// ---------------- constants ----------------
#define SEQ     4096
#define IN_DIM  1024
#define D_MODEL 512
#define D_INNER 1024
#define D_STATE 16
#define DT_RANK 32

#define CHUNK   32
#define NCHUNK  128    // SEQ / CHUNK
#define NREC    16384  // D_INNER * D_STATE

#define LOG2E 1.44269504088896f

// ---------------- workspace layout (float offsets) ----------------
// ws_size = 256 MiB (poison fill = 2.684e8 B). We use ~97.5 MB.
// SIZES IN FLOAT-EQUIVALENTS (ushort buffers take count/2 floats):
//   hn_bf = 4096*512 us = 1,048,576 fl  <-- was under-budgeted 2x in r8/r9 (THE BUG)
static const size_t OFF_H     = 0;                       // h f32 (2M fl)
static const size_t OFF_PS    = 2097152;                 // xcraw f32 (4M) -> P(2M)+S(2M) -> y_bf (2M)
static const size_t OFF_Z     = 6291456;                 // z f32 (4M)
static const size_t OFF_XC    = 10485760;                // xc f32 (4M)
static const size_t OFF_DT    = 14680064;                // dt f32 (4M); transients: x_bf, xc_bf (2M each)
static const size_t OFF_CARRY = 18874368;                // carry f32 (2M)
static const size_t OFF_HNB   = 20971520;                // hn_bf (1,048,576 fl)  ends 22,020,096
static const size_t OFF_FC1WB = 22020096;                // fc1w_bf (262,144 fl)  ends 22,282,240
static const size_t OFF_WIB   = 22282240;                // Wi_bf 2 layers (1,048,576 fl) ends 23,330,816
static const size_t OFF_XPWB  = 23330816;                // xpw_bf 2 layers (65,536 fl)  ends 23,396,352
static const size_t OFF_DPWB  = 23396352;                // dpw_bf 2 layers (32,768 fl)  ends 23,429,120
static const size_t OFF_DBCF  = 23429120;                // dbc f32 (262,144 fl)         ends 23,691,264
static const size_t OFF_DBCB  = 23691264;                // dbc_bf (131,072 fl)          ends 23,822,336
static const size_t OFF_WOUTB = 23822336;                // wout_bf 2 layers (524,288 fl) ends 24,346,624
static const size_t OFF_PART  = 24346624;                // 32*512 doubles (32,768 fl)   ends 24,379,392
// end = 24,379,392 fl = 97.5 MB

typedef __attribute__((ext_vector_type(8))) short bf16x8;
typedef __attribute__((ext_vector_type(4))) float f32x4;

// ---------------- jax threefry / normal reproduction (VALIDATED round 4) ----------------
__device__ __forceinline__ uint32_t rotl32(uint32_t v, int r) { return (v << r) | (v >> (32 - r)); }

__device__ __forceinline__ void threefry2x32(uint32_t k0, uint32_t k1, uint32_t x0, uint32_t x1,
                                             uint32_t& o0, uint32_t& o1) {
  uint32_t ks0 = k0, ks1 = k1, ks2 = k0 ^ k1 ^ 0x1BD11BDAu;
  x0 += ks0; x1 += ks1;
  const int rotA[4] = {13, 15, 26, 6};
  const int rotB[4] = {17, 29, 16, 24};
  uint32_t ks[3] = {ks0, ks1, ks2};
#pragma unroll
  for (int r = 0; r < 5; ++r) {
    const int* rr = (r & 1) ? rotB : rotA;
#pragma unroll
    for (int j = 0; j < 4; ++j) { x0 += x1; x1 = rotl32(x1, rr[j]); x1 ^= x0; }
    x0 += ks[(r + 1) % 3];
    x1 += ks[(r + 2) % 3] + (uint32_t)(r + 1);
  }
  o0 = x0; o1 = x1;
}

__device__ __forceinline__ float erfinv32(float x) {
  float w = -log1pf(-x * x);
  float p;
  if (w < 5.0f) {
    w -= 2.5f;
    p = 2.81022636e-08f;
    p = fmaf(p, w, 3.43273939e-07f);
    p = fmaf(p, w, -3.5233877e-06f);
    p = fmaf(p, w, -4.39150654e-06f);
    p = fmaf(p, w, 0.00021858087f);
    p = fmaf(p, w, -0.00125372503f);
    p = fmaf(p, w, -0.00417768164f);
    p = fmaf(p, w, 0.246640727f);
    p = fmaf(p, w, 1.50140941f);
  } else {
    w = sqrtf(w) - 3.0f;
    p = -0.000200214257f;
    p = fmaf(p, w, 0.000100950558f);
    p = fmaf(p, w, 0.00134934322f);
    p = fmaf(p, w, -0.00367342844f);
    p = fmaf(p, w, 0.00573950773f);
    p = fmaf(p, w, -0.0076224613f);
    p = fmaf(p, w, 0.00943887047f);
    p = fmaf(p, w, 1.00167406f);
    p = fmaf(p, w, 2.83297682f);
  }
  return p * x;
}

__device__ __forceinline__ float bits_to_normal(uint32_t b) {
  float f = __uint_as_float((b >> 9) | 0x3f800000u) - 1.0f;
  const float lo = -0.99999994f;
  float u = f * (1.0f - lo) + lo;
  u = fmaxf(lo, u);
  return 1.41421356f * erfinv32(u);
}

// ---------------- bf16 conversion (RNE) ----------------
__device__ __forceinline__ ushort f2bf(float x) {
  uint32_t u = __float_as_uint(x);
  u = (u + 0x7FFFu + ((u >> 16) & 1u)) >> 16;
  return (ushort)u;
}
__device__ __forceinline__ bf16x8 pack8(float4 a, float4 b) {
  bf16x8 v;
  v[0] = f2bf(a.x); v[1] = f2bf(a.y); v[2] = f2bf(a.z); v[3] = f2bf(a.w);
  v[4] = f2bf(b.x); v[5] = f2bf(b.y); v[6] = f2bf(b.z); v[7] = f2bf(b.w);
  return v;
}

// PARTITIONABLE threefry bits -> bf16 weights directly (VALIDATED)
__global__ __launch_bounds__(256) void gen_wout(ushort* __restrict__ w) {
  int gid = blockIdx.x * 256 + threadIdx.x;        // [0, 2*524288)
  int layer = gid >> 19;
  int j = gid & 0x7FFFF;
  uint32_t k0, k1;
  threefry2x32(0u, 7u, 0u, (uint32_t)layer, k0, k1);   // fold_in(key(7), layer)
  uint32_t o0, o1;
  threefry2x32(k0, k1, 0u, (uint32_t)j, o0, o1);
  w[(size_t)layer * 524288 + j] = f2bf(bits_to_normal(o0 ^ o1) * 0.02f);
}

// ---------------- fused f32 -> bf16 conversion of all GEMM inputs (one dispatch) ----------------
// 8-elem chunks: x 524288 | fc1_w 65536 | in_proj(2L) 262144 | x_proj(2L) 16384 | dt_proj(2L) 8192
__global__ __launch_bounds__(256) void convert_all(
    const float* __restrict__ x,   const float* __restrict__ fc1w,
    const float* __restrict__ ipw, const float* __restrict__ xpw,
    const float* __restrict__ dpw,
    ushort* __restrict__ xb, ushort* __restrict__ fc1wb, ushort* __restrict__ ipwb,
    ushort* __restrict__ xpwb, ushort* __restrict__ dpwb) {
  int gid = blockIdx.x * 256 + threadIdx.x;
  const float* src; ushort* dst; size_t off;
  if (gid < 524288)      { src = x;    dst = xb;    off = gid; }
  else if (gid < 589824) { src = fc1w; dst = fc1wb; off = gid - 524288; }
  else if (gid < 851968) { src = ipw;  dst = ipwb;  off = gid - 589824; }
  else if (gid < 868352) { src = xpw;  dst = xpwb;  off = gid - 851968; }
  else if (gid < 876544) { src = dpw;  dst = dpwb;  off = gid - 868352; }
  else return;
  const float4* p = (const float4*)(src + off * 8);
  *(bf16x8*)(dst + off * 8) = pack8(p[0], p[1]);
}

// ---------------- activations ----------------
__device__ __forceinline__ float silu_f(float v) { return v / (1.0f + exp2f(-LOG2E * v)); }
__device__ __forceinline__ float gelu_f(float v) {
  float v3 = v * v * v;
  return 0.5f * v * (1.0f + tanhf(0.7978845608028654f * (v + 0.044715f * v3)));
}
__device__ __forceinline__ float softplus_f(float v) {
  return fmaxf(v, 0.0f) + log1pf(exp2f(-LOG2E * fabsf(v)));
}

// ---------------- bf16 MFMA GEMM 64xNT (validated round 8) ----------------
enum { EPI_NONE = 0, EPI_BIAS_GELU = 1, EPI_INPROJ = 2, EPI_SOFTPLUS = 3, EPI_RESID = 4, EPI_DBC = 5 };

template <int EPI, int NT>
__global__ __launch_bounds__(256) void gemm_bf(
    const ushort* __restrict__ A, int lda,
    const ushort* __restrict__ B, int ldb,
    float* __restrict__ C, int ldc, int K,
    const float* __restrict__ bias, float* __restrict__ out2,
    ushort* __restrict__ outb) {
  constexpr int NB = NT / 64;
  __shared__ ushort As[2][64][40];
  __shared__ ushort Bs[2][NT][40];
  const int m0 = blockIdx.y * 64, n0 = blockIdx.x * NT;
  const int tid = threadIdx.x;
  const int arow = tid >> 2, ach = (tid & 3) * 8;
  const int lane = tid & 63, wid = tid >> 6;
  const int lr = lane & 15, lhi = lane >> 4;
  const ushort* Ap  = A + (size_t)(m0 + arow) * lda + ach;
  const ushort* Bp0 = B + (size_t)(n0 + arow) * ldb + ach;
  const ushort* Bp1 = (NB > 1) ? (B + (size_t)(n0 + 64 + arow) * ldb + ach) : Bp0;

  f32x4 acc[NT / 16] = {};
  uint4 ra, rb0, rb1;

  ra  = *(const uint4*)Ap;
  rb0 = *(const uint4*)Bp0;
  if (NB > 1) rb1 = *(const uint4*)Bp1;
  *(uint4*)&As[0][arow][ach] = ra;
  *(uint4*)&Bs[0][arow][ach] = rb0;
  if (NB > 1) *(uint4*)&Bs[0][64 + arow][ach] = rb1;
  __syncthreads();

  const int nk = K >> 5;
  int cur = 0;
  for (int ki = 0; ki < nk; ++ki) {
    const bool more = (ki + 1 < nk);
    if (more) {
      const int k = (ki + 1) << 5;
      ra  = *(const uint4*)(Ap + k);
      rb0 = *(const uint4*)(Bp0 + k);
      if (NB > 1) rb1 = *(const uint4*)(Bp1 + k);
    }
    bf16x8 af = *(const bf16x8*)&As[cur][wid * 16 + lr][lhi * 8];
#pragma unroll
    for (int t = 0; t < NT / 16; ++t) {
      bf16x8 bv = *(const bf16x8*)&Bs[cur][t * 16 + lr][lhi * 8];
      acc[t] = __builtin_amdgcn_mfma_f32_16x16x32_bf16(af, bv, acc[t], 0, 0, 0);
    }
    if (more) {
      *(uint4*)&As[cur ^ 1][arow][ach] = ra;
      *(uint4*)&Bs[cur ^ 1][arow][ach] = rb0;
      if (NB > 1) *(uint4*)&Bs[cur ^ 1][64 + arow][ach] = rb1;
    }
    __syncthreads();
    cur ^= 1;
  }

#pragma unroll
  for (int t = 0; t < NT / 16; ++t) {
    const int n = n0 + t * 16 + lr;
#pragma unroll
    for (int r = 0; r < 4; ++r) {
      const int m = m0 + wid * 16 + lhi * 4 + r;
      float v = acc[t][r];
      if (EPI == EPI_NONE) {
        C[(size_t)m * ldc + n] = v;
      } else if (EPI == EPI_BIAS_GELU) {
        v += bias[n];
        C[(size_t)m * ldc + n] = gelu_f(v);
      } else if (EPI == EPI_SOFTPLUS) {
        v += bias[n];
        C[(size_t)m * ldc + n] = softplus_f(v);
      } else if (EPI == EPI_RESID) {
        C[(size_t)m * ldc + n] += v;
      } else if (EPI == EPI_INPROJ) {
        if (n < D_INNER) C[(size_t)m * D_INNER + n] = v;
        else             out2[(size_t)m * D_INNER + (n - D_INNER)] = silu_f(v);
      } else if (EPI == EPI_DBC) {
        C[(size_t)m * 64 + n] = v;
        outb[(size_t)m * 64 + n] = f2bf(v);
      }
    }
  }
}

// ---------------- bf16 MFMA GEMM 128x128 ----------------
template <int EPI>
__global__ __launch_bounds__(256) void gemm_bf128(
    const ushort* __restrict__ A, int lda,
    const ushort* __restrict__ B, int ldb,
    float* __restrict__ C, int ldc, int K,
    const float* __restrict__ bias, float* __restrict__ out2) {
  __shared__ ushort As[2][128][40];
  __shared__ ushort Bs[2][128][40];
  const int m0 = blockIdx.y * 128, n0 = blockIdx.x * 128;
  const int tid = threadIdx.x;
  const int lane = tid & 63, wid = tid >> 6;
  const int lr = lane & 15, lhi = lane >> 4;
  const int r0_ = tid >> 2, ach = (tid & 3) * 8;
  const ushort* Ap0 = A + (size_t)(m0 + r0_) * lda + ach;
  const ushort* Ap1 = A + (size_t)(m0 + r0_ + 64) * lda + ach;
  const ushort* Bp0 = B + (size_t)(n0 + r0_) * ldb + ach;
  const ushort* Bp1 = B + (size_t)(n0 + r0_ + 64) * ldb + ach;

  f32x4 acc[16] = {};   // [fr*8 + t]
  uint4 ra0, ra1, rb0, rb1;

  ra0 = *(const uint4*)Ap0; ra1 = *(const uint4*)Ap1;
  rb0 = *(const uint4*)Bp0; rb1 = *(const uint4*)Bp1;
  *(uint4*)&As[0][r0_][ach] = ra0; *(uint4*)&As[0][r0_ + 64][ach] = ra1;
  *(uint4*)&Bs[0][r0_][ach] = rb0; *(uint4*)&Bs[0][r0_ + 64][ach] = rb1;
  __syncthreads();

  const int nk = K >> 5;
  int cur = 0;
  for (int ki = 0; ki < nk; ++ki) {
    const bool more = (ki + 1 < nk);
    if (more) {
      const int k = (ki + 1) << 5;
      ra0 = *(const uint4*)(Ap0 + k); ra1 = *(const uint4*)(Ap1 + k);
      rb0 = *(const uint4*)(Bp0 + k); rb1 = *(const uint4*)(Bp1 + k);
    }
    bf16x8 af0 = *(const bf16x8*)&As[cur][wid * 32 + lr][lhi * 8];
    bf16x8 af1 = *(const bf16x8*)&As[cur][wid * 32 + 16 + lr][lhi * 8];
#pragma unroll
    for (int t = 0; t < 8; ++t) {
      bf16x8 bv = *(const bf16x8*)&Bs[cur][t * 16 + lr][lhi * 8];
      acc[t]     = __builtin_amdgcn_mfma_f32_16x16x32_bf16(af0, bv, acc[t], 0, 0, 0);
      acc[8 + t] = __builtin_amdgcn_mfma_f32_16x16x32_bf16(af1, bv, acc[8 + t], 0, 0, 0);
    }
    if (more) {
      *(uint4*)&As[cur ^ 1][r0_][ach] = ra0; *(uint4*)&As[cur ^ 1][r0_ + 64][ach] = ra1;
      *(uint4*)&Bs[cur ^ 1][r0_][ach] = rb0; *(uint4*)&Bs[cur ^ 1][r0_ + 64][ach] = rb1;
    }
    __syncthreads();
    cur ^= 1;
  }

#pragma unroll
  for (int fr = 0; fr < 2; ++fr) {
#pragma unroll
    for (int t = 0; t < 8; ++t) {
      const int n = n0 + t * 16 + lr;
#pragma unroll
      for (int r = 0; r < 4; ++r) {
        const int m = m0 + wid * 32 + fr * 16 + lhi * 4 + r;
        float v = acc[fr * 8 + t][r];
        if (EPI == EPI_INPROJ) {
          if (n < D_INNER) C[(size_t)m * D_INNER + n] = v;
          else             out2[(size_t)m * D_INNER + (n - D_INNER)] = silu_f(v);
        } else {
          C[(size_t)m * ldc + n] = v;
        }
      }
    }
  }
}

// ---------------- layernorm (validated) ----------------
template <int BF>
__global__ __launch_bounds__(256) void ln_rows(const float* __restrict__ in,
                                               const float* __restrict__ w,
                                               const float* __restrict__ b,
                                               float* __restrict__ outf,
                                               ushort* __restrict__ outb) {
  __shared__ double red[4];
  const int row = blockIdx.x, t = threadIdx.x;
  const float* r = in + (size_t)row * D_MODEL;
  double x0 = (double)r[t], x1 = (double)r[t + 256];
  double s = x0 + x1;
#pragma unroll
  for (int o = 32; o >= 1; o >>= 1) s += __shfl_down(s, o);
  int wid = t >> 6, lane = t & 63;
  if (lane == 0) red[wid] = s;
  __syncthreads();
  double mu = (red[0] + red[1] + red[2] + red[3]) * (1.0 / 512.0);
  __syncthreads();
  double d0 = x0 - mu, d1 = x1 - mu;
  double v = d0 * d0 + d1 * d1;
#pragma unroll
  for (int o = 32; o >= 1; o >>= 1) v += __shfl_down(v, o);
  if (lane == 0) red[wid] = v;
  __syncthreads();
  double var = (red[0] + red[1] + red[2] + red[3]) * (1.0 / 512.0);
  double rs = rsqrt(var + 1e-5);
  float o0 = (float)(d0 * rs * (double)w[t] + (double)b[t]);
  float o1 = (float)(d1 * rs * (double)w[t + 256] + (double)b[t + 256]);
  if (BF) {
    outb[(size_t)row * D_MODEL + t]       = f2bf(o0);
    outb[(size_t)row * D_MODEL + t + 256] = f2bf(o1);
  } else {
    outf[(size_t)row * D_MODEL + t]       = o0;
    outf[(size_t)row * D_MODEL + t + 256] = o1;
  }
}

// ---------------- causal depthwise conv + bias + silu (validated) ----------------
__global__ __launch_bounds__(256) void conv_silu2(const float* __restrict__ xcr,
                                                  const float* __restrict__ cw,
                                                  const float* __restrict__ cb,
                                                  float* __restrict__ outf,
                                                  ushort* __restrict__ outb) {
  const int l = blockIdx.x;
  for (int q = 0; q < 4; ++q) {
    const int d = threadIdx.x + q * 256;
    float acc = cb[d];
#pragma unroll
    for (int k = 0; k < 4; ++k) {
      const int ll = l + k - 3;
      const float xv = (ll >= 0) ? xcr[(size_t)ll * D_INNER + d] : 0.0f;
      acc = fmaf(xv, cw[d * 4 + k], acc);
    }
    float o = silu_f(acc);
    outf[(size_t)l * D_INNER + d] = o;
    outb[(size_t)l * D_INNER + d] = f2bf(o);
  }
}

// ---------------- selective scan (validated round 7/8) ----------------
__global__ __launch_bounds__(256) void scanA(const float* __restrict__ dt,
                                             const float* __restrict__ dbc,
                                             const float* __restrict__ xc,
                                             const float* __restrict__ Alog,
                                             float* __restrict__ P, float* __restrict__ S) {
  const int c = blockIdx.y;
  const int d = blockIdx.x * 256 + threadIdx.x;
  float a2[16], s[16];
#pragma unroll
  for (int q = 0; q < 4; ++q) {
    float4 al = *(const float4*)(Alog + (size_t)d * 16 + q * 4);
    a2[4*q+0] = -expf(al.x) * LOG2E; a2[4*q+1] = -expf(al.y) * LOG2E;
    a2[4*q+2] = -expf(al.z) * LOG2E; a2[4*q+3] = -expf(al.w) * LOG2E;
  }
#pragma unroll
  for (int n = 0; n < 16; ++n) s[n] = 0.0f;
  float sdt = 0.0f;
  const int l0 = c * CHUNK;
#pragma unroll 2
  for (int t = 0; t < CHUNK; ++t) {
    const int l = l0 + t;
    const float dtv = dt[(size_t)l * D_INNER + d];
    const float xv  = xc[(size_t)l * D_INNER + d];
    const float dx = dtv * xv;
    sdt += dtv;
    float bv[16];
    const float4* B4 = (const float4*)(dbc + (size_t)l * 64 + DT_RANK);
    *(float4*)&bv[0]  = B4[0]; *(float4*)&bv[4]  = B4[1];
    *(float4*)&bv[8]  = B4[2]; *(float4*)&bv[12] = B4[3];
#pragma unroll
    for (int n = 0; n < 16; ++n)
      s[n] = fmaf(exp2f(dtv * a2[n]), s[n], bv[n] * dx);
  }
  float4* Sp = (float4*)(S + (size_t)c * NREC + (size_t)d * 16);
  float4* Pp = (float4*)(P + (size_t)c * NREC + (size_t)d * 16);
#pragma unroll
  for (int q = 0; q < 4; ++q) {
    Sp[q] = make_float4(s[4*q], s[4*q+1], s[4*q+2], s[4*q+3]);
    Pp[q] = make_float4(exp2f(a2[4*q]*sdt), exp2f(a2[4*q+1]*sdt),
                        exp2f(a2[4*q+2]*sdt), exp2f(a2[4*q+3]*sdt));
  }
}

__global__ __launch_bounds__(256) void scanB(const float* __restrict__ P,
                                             const float* __restrict__ S,
                                             float* __restrict__ carry) {
  int idx = blockIdx.x * 256 + threadIdx.x;
  float cr = 0.0f;
  for (int c = 0; c < NCHUNK; ++c) {
    size_t k = (size_t)c * NREC + idx;
    carry[k] = cr;
    cr = fmaf(P[k], cr, S[k]);
  }
}

__global__ __launch_bounds__(256) void scanC(const float* __restrict__ dt,
                                             const float* __restrict__ dbc,
                                             const float* __restrict__ xc,
                                             const float* __restrict__ Alog,
                                             const float* __restrict__ carry,
                                             const float* __restrict__ Dskip,
                                             const float* __restrict__ zs,
                                             ushort* __restrict__ yb) {
  const int c = blockIdx.y;
  const int d = blockIdx.x * 256 + threadIdx.x;
  float a2[16], s[16];
#pragma unroll
  for (int q = 0; q < 4; ++q) {
    float4 al = *(const float4*)(Alog + (size_t)d * 16 + q * 4);
    a2[4*q+0] = -expf(al.x) * LOG2E; a2[4*q+1] = -expf(al.y) * LOG2E;
    a2[4*q+2] = -expf(al.z) * LOG2E; a2[4*q+3] = -expf(al.w) * LOG2E;
    float4 cr = *(const float4*)(carry + (size_t)c * NREC + (size_t)d * 16 + q * 4);
    s[4*q+0] = cr.x; s[4*q+1] = cr.y; s[4*q+2] = cr.z; s[4*q+3] = cr.w;
  }
  const float dsk = Dskip[d];
  const int l0 = c * CHUNK;
#pragma unroll 2
  for (int t = 0; t < CHUNK; ++t) {
    const int l = l0 + t;
    const float dtv = dt[(size_t)l * D_INNER + d];
    const float xv  = xc[(size_t)l * D_INNER + d];
    const float dx = dtv * xv;
    float bv[16], cv[16];
    const float4* B4 = (const float4*)(dbc + (size_t)l * 64 + DT_RANK);
    *(float4*)&bv[0]  = B4[0]; *(float4*)&bv[4]  = B4[1];
    *(float4*)&bv[8]  = B4[2]; *(float4*)&bv[12] = B4[3];
    *(float4*)&cv[0]  = B4[4]; *(float4*)&cv[4]  = B4[5];
    *(float4*)&cv[8]  = B4[6]; *(float4*)&cv[12] = B4[7];
    float acc = 0.0f;
#pragma unroll
    for (int n = 0; n < 16; ++n) {
      s[n] = fmaf(exp2f(dtv * a2[n]), s[n], bv[n] * dx);
      acc = fmaf(s[n], cv[n], acc);
    }
    float yv = fmaf(xv, dsk, acc);
    yb[(size_t)l * D_INNER + d] = f2bf(yv * zs[(size_t)l * D_INNER + d]);
  }
}

// ---------------- final head (validated) ----------------
__global__ __launch_bounds__(512) void colsum(const float* __restrict__ h, double* __restrict__ part) {
  int d = threadIdx.x;
  int r0 = blockIdx.x * 128;
  double s = 0.0;
  for (int r = 0; r < 128; ++r) s += (double)h[(size_t)(r0 + r) * D_MODEL + d];
  part[blockIdx.x * D_MODEL + d] = s;
}

__global__ __launch_bounds__(512) void head_k(const double* __restrict__ part,
                                              const float* __restrict__ cls_w,
                                              const float* __restrict__ cls_b,
                                              float* __restrict__ out) {
  __shared__ double l0[512], l1[512];
  int d = threadIdx.x;
  double s = 0.0;
  for (int b = 0; b < 32; ++b) s += part[b * D_MODEL + d];
  double hv = s * (1.0 / 4096.0);
  out[d] = (float)hv;
  l0[d] = hv * (double)cls_w[d];
  l1[d] = hv * (double)cls_w[D_MODEL + d];
  __syncthreads();
  for (int o = 256; o > 0; o >>= 1) {
    if (d < o) { l0[d] += l0[d + o]; l1[d] += l1[d + o]; }
    __syncthreads();
  }
  if (d == 0) { out[512] = (float)(l0[0] + (double)cls_b[0]); out[513] = (float)(l1[0] + (double)cls_b[1]); }
}

// ---------------- launch ----------------
extern "C" void kernel_launch(void* const* d_in, const int* in_sizes, int n_in,
                              void* d_out, int out_size, void* d_ws, size_t ws_size,
                              hipStream_t stream) {
  const float* x         = (const float*)d_in[0];
  const float* fc1_w     = (const float*)d_in[1];
  const float* fc1_b     = (const float*)d_in[2];
  const float* ln_w      = (const float*)d_in[3];
  const float* ln_b      = (const float*)d_in[4];
  const float* in_proj_w = (const float*)d_in[5];
  const float* conv_w    = (const float*)d_in[6];
  const float* conv_b    = (const float*)d_in[7];
  const float* x_proj_w  = (const float*)d_in[8];
  const float* dt_proj_w = (const float*)d_in[9];
  const float* dt_proj_b = (const float*)d_in[10];
  const float* A_log     = (const float*)d_in[11];
  const float* D_skip    = (const float*)d_in[12];
  const float* norm_w    = (const float*)d_in[13];
  const float* norm_b    = (const float*)d_in[14];
  const float* cls_w     = (const float*)d_in[15];
  const float* cls_b     = (const float*)d_in[16];
  float* out = (float*)d_out;
  float* ws  = (float*)d_ws;

  float*  h_buf   = ws + OFF_H;
  float*  xcraw   = ws + OFF_PS;
  float*  P_buf   = ws + OFF_PS;
  float*  S_buf   = ws + OFF_PS + 2097152;
  ushort* y_bf    = (ushort*)(ws + OFF_PS);
  float*  z_buf   = ws + OFF_Z;
  float*  xc_buf  = ws + OFF_XC;
  float*  dt_buf  = ws + OFF_DT;
  ushort* x_bf    = (ushort*)(ws + OFF_DT);       // transient (pre-fc1)
  ushort* xc_bf   = (ushort*)(ws + OFF_DT);       // transient (conv -> dbc GEMM)
  float*  carry_b = ws + OFF_CARRY;
  ushort* hn_bf   = (ushort*)(ws + OFF_HNB);
  ushort* fc1w_bf = (ushort*)(ws + OFF_FC1WB);
  ushort* Wi_bf   = (ushort*)(ws + OFF_WIB);      // both layers
  ushort* xpw_bf  = (ushort*)(ws + OFF_XPWB);     // both layers
  ushort* dpw_bf  = (ushort*)(ws + OFF_DPWB);     // both layers
  float*  dbc_f   = ws + OFF_DBCF;
  ushort* dbc_bf  = (ushort*)(ws + OFF_DBCB);
  ushort* wout_bf = (ushort*)(ws + OFF_WOUTB);    // both layers
  double* part    = (double*)(ws + OFF_PART);

  gen_wout<<<4096, 256, 0, stream>>>(wout_bf);
  convert_all<<<3424, 256, 0, stream>>>(x, fc1_w, in_proj_w, x_proj_w, dt_proj_w,
                                        x_bf, fc1w_bf, Wi_bf, xpw_bf, dpw_bf);

  // h = gelu(x @ fc1_w^T + fc1_b)
  gemm_bf<EPI_BIAS_GELU, 128><<<dim3(4, 64), 256, 0, stream>>>(
      x_bf, IN_DIM, fc1w_bf, IN_DIM, h_buf, D_MODEL, IN_DIM, fc1_b, nullptr, nullptr);

  for (int i = 0; i < 2; ++i) {
    // hn = LN(h) -> bf16
    ln_rows<1><<<4096, 256, 0, stream>>>(h_buf, ln_w + i * D_MODEL, ln_b + i * D_MODEL,
                                         nullptr, hn_bf);
    // xz = hn @ Wi^T -> xcraw f32 (n<1024), silu(z) f32 (n>=1024)  [128x128 tiles]
    gemm_bf128<EPI_INPROJ><<<dim3(16, 32), 256, 0, stream>>>(
        hn_bf, D_MODEL, Wi_bf + (size_t)i * 1048576, D_MODEL, xcraw, D_INNER, D_MODEL,
        nullptr, z_buf);
    // xc = silu(conv(xcraw)+cb) -> f32 + bf16
    conv_silu2<<<4096, 256, 0, stream>>>(xcraw, conv_w + (size_t)i * D_INNER * 4,
                                         conv_b + i * D_INNER, xc_buf, xc_bf);
    // dbc = xc @ x_proj_w^T -> f32 + bf16
    gemm_bf<EPI_DBC, 64><<<dim3(1, 64), 256, 0, stream>>>(
        xc_bf, D_INNER, xpw_bf + (size_t)i * 65536, D_INNER, dbc_f, 64, D_INNER,
        nullptr, nullptr, dbc_bf);
    // dt = softplus(dbc[:, :32] @ dt_proj_w^T + dt_proj_b)
    gemm_bf<EPI_SOFTPLUS, 128><<<dim3(8, 64), 256, 0, stream>>>(
        dbc_bf, 64, dpw_bf + (size_t)i * 32768, DT_RANK, dt_buf, D_INNER, DT_RANK,
        dt_proj_b + i * D_INNER, nullptr, nullptr);
    // selective scan -> y bf16
    const float* Alog_i = A_log + (size_t)i * D_INNER * D_STATE;
    scanA<<<dim3(4, NCHUNK), 256, 0, stream>>>(dt_buf, dbc_f, xc_buf, Alog_i, P_buf, S_buf);
    scanB<<<64, 256, 0, stream>>>(P_buf, S_buf, carry_b);
    scanC<<<dim3(4, NCHUNK), 256, 0, stream>>>(dt_buf, dbc_f, xc_buf, Alog_i, carry_b,
                                               D_skip + i * D_INNER, z_buf, y_bf);
    // h += y @ wout^T
    gemm_bf<EPI_RESID, 128><<<dim3(4, 64), 256, 0, stream>>>(
        y_bf, D_INNER, wout_bf + (size_t)i * 524288, D_INNER, h_buf, D_MODEL, D_INNER,
        nullptr, nullptr, nullptr);
  }

  ln_rows<0><<<4096, 256, 0, stream>>>(h_buf, norm_w, norm_b, out + 514, nullptr);
  colsum<<<32, 512, 0, stream>>>(out + 514, part);
  head_k<<<1, 512, 0, stream>>>(part, cls_w, cls_b, out);
}